// Round 5
// baseline (332.717 us; speedup 1.0000x reference)
//
#include <hip/hip_runtime.h>
#include <hip/hip_bf16.h>

// Problem constants: BS=8, Q=128, S1=32, S2=64, H=768, NH=12, DH=64.

typedef __attribute__((ext_vector_type(8))) short short8;
typedef __attribute__((ext_vector_type(4))) short short4v;
typedef __attribute__((ext_vector_type(4))) float f32x4;

__device__ __forceinline__ short f2bf(float f) {
  __hip_bfloat16 b = __float2bfloat16(f);
  return __builtin_bit_cast(short, b);
}
__device__ __forceinline__ float bf2f(short s) {
  __hip_bfloat16 b = __builtin_bit_cast(__hip_bfloat16, s);
  return __bfloat162float(b);
}

#define MFMA16(a, b, c) __builtin_amdgcn_mfma_f32_16x16x32_bf16((a), (b), (c), 0, 0, 0)

// async 16B/lane global->LDS (wave-uniform LDS base; HW adds lane*16)
__device__ __forceinline__ void async_load16(const void* g, void* l) {
  auto l3 = (__attribute__((address_space(3))) void*)(uintptr_t)(
      reinterpret_cast<uintptr_t>(l));
  auto g1 = (const __attribute__((address_space(1))) void*)g;
  __builtin_amdgcn_global_load_lds(g1, l3, 16, 0, 0);
}

// raw barrier (no implicit vmcnt(0) drain) + compiler memory fence
#define KBAR()                                      \
  do {                                              \
    asm volatile("" ::: "memory");                  \
    __builtin_amdgcn_s_barrier();                   \
    asm volatile("" ::: "memory");                  \
  } while (0)
#define VMW(N) asm volatile("s_waitcnt vmcnt(" #N ")" ::: "memory")

// ---------------------------------------------------------------------------
// prep: blocks [0,3456) = 6 weight transposes (fp32 -> bf16, WT[n][k]);
//       blocks [3456,16224) = fp32->bf16 convert of q/k/v/kvec.
// ---------------------------------------------------------------------------
__global__ __launch_bounds__(256)
void prep(const float* __restrict__ w0, const float* __restrict__ w1,
          const float* __restrict__ w2, const float* __restrict__ w3,
          const float* __restrict__ w4, const float* __restrict__ w5,
          short* __restrict__ WT,
          const float* __restrict__ q_in, const float* __restrict__ k_in,
          const float* __restrict__ v_in, const float* __restrict__ kvec,
          short* __restrict__ qbf, short* __restrict__ kbf,
          short* __restrict__ vbf, short* __restrict__ kvb) {
  const int id = blockIdx.x;
  const int tid = threadIdx.x;
  if (id < 3456) {
    __shared__ float tile[32][33];
    const int zz = id / 576, r = id % 576;
    const float* W = (zz == 0) ? w0 : (zz == 1) ? w1 : (zz == 2) ? w2
                   : (zz == 3) ? w3 : (zz == 4) ? w4 : w5;
    short* WTo = WT + (size_t)zz * 768 * 768;
    const int bx = (r % 24) * 32, by = (r / 24) * 32;
    const int tx = tid & 31, ty = tid >> 5;  // 32 x 8
    #pragma unroll
    for (int i = 0; i < 32; i += 8)
      tile[ty + i][tx] = W[(size_t)(by + ty + i) * 768 + bx + tx];
    __syncthreads();
    #pragma unroll
    for (int i = 0; i < 32; i += 8)
      WTo[(size_t)(bx + ty + i) * 768 + by + tx] = f2bf(tile[tx][ty + i]);
    return;
  }
  // ---- cvt: short8 units: q 98304 | k 1572864 | v 1572864 | kvec 24576 ----
  const int i = (id - 3456) * 256 + tid;
  const float* src;
  short* dst;
  int idx;
  if (i < 98304)        { src = q_in; dst = qbf; idx = i; }
  else if (i < 1671168) { src = k_in; dst = kbf; idx = i - 98304; }
  else if (i < 3244032) { src = v_in; dst = vbf; idx = i - 1671168; }
  else                  { src = kvec; dst = kvb; idx = i - 3244032; }
  const float4* s = (const float4*)src + (size_t)idx * 2;
  const float4 a = s[0], b = s[1];
  __align__(16) short tmp[8] = {f2bf(a.x), f2bf(a.y), f2bf(a.z), f2bf(a.w),
                                f2bf(b.x), f2bf(b.y), f2bf(b.z), f2bf(b.w)};
  *((short8*)dst + idx) = *(short8*)tmp;
}

// ---------------------------------------------------------------------------
// All projections, one launch, grid (128, 3, 3), 512 threads, 96 KiB dyn LDS:
//   z<2 : kv GEMM, 128x256 tile (M x N), BK=64, 2-phase-per-K-tile schedule.
//         768 kv blocks = exactly 3 full rounds on 256 CUs (fixes the
//         half-empty round-2 of the 256^2 geometry). Wave tile 64x64.
//         Per phase: {ds reads + 2-4 stage loads; bar; 16 MFMA; bar} — same
//         per-phase MFMA density (620 cyc/CU) as the proven 8-phase body,
//         half the barriers per MFMA.
//   z==2: EXACT previous gemm_small body (BK=32, 256 active threads; threads
//         256-511 only participate in barriers). 108 active blocks.
// ---------------------------------------------------------------------------
__global__ __launch_bounds__(512, 2)
void gemm_proj(const short* __restrict__ kbf, const short* __restrict__ vbf,
               const short* __restrict__ qbf, const short* __restrict__ kvb,
               const short* __restrict__ WT6,
               const float* __restrict__ wk_b, const float* __restrict__ wv_b,
               const float* __restrict__ wq_b, const float* __restrict__ sq_b,
               const float* __restrict__ sk_b,
               short* __restrict__ kp, short* __restrict__ vT,
               short* __restrict__ qp, float* __restrict__ sqp,
               float* __restrict__ skp) {
  const int K = 768, WELEM = 768 * 768;
  extern __shared__ __align__(16) char smem_c[];
  short* smem = (short*)smem_c;
  const int tid = threadIdx.x;
  const int w = tid >> 6, lane = tid & 63, quad = lane >> 4, l16 = lane & 15;
  const f32x4 zero4 = {0.f, 0.f, 0.f, 0.f};

  if (blockIdx.z < 2) {
    // ============ kv branch: 128x256 tile, BK=64, 2-phase/K-tile ===========
    short* LA = smem;                  // [2 buf][128 rows][64 cols] bf16 32K
    short* LB = smem + 2 * 128 * 64;   // [2 buf][256 rows][64 cols] bf16 64K
    const int z = blockIdx.z;
    const short* Ag = z ? vbf : kbf;
    const short* Bg = z ? (WT6 + 3 * WELEM) : (WT6 + 2 * WELEM);
    const float* bias = z ? wv_b : wk_b;
    const int m0 = blockIdx.x * 128, n0 = blockIdx.y * 256;
    const int wr = w >> 2, wc = w & 3;  // 2 x 4 wave grid; wave tile 64x64

    // staging geometry: thread covers row (w*8 + lane/8), swizzled chunk
    // LDS[r][c] = G[r][c ^ (r&7)]  (chunk = 8 bf16 = 16B)
    const int srow = lane >> 3;              // 0..7
    const int schk = (lane & 7) ^ srow;      // pre-swizzled global chunk
    const short* ag0 = Ag + (size_t)(m0 + w * 8 + srow) * K + schk * 8;
    const short* bg0 = Bg + (size_t)(n0 + w * 8 + srow) * K + schk * 8;
    short* la0 = LA + (w * 8) * 64;          // wave-uniform LDS bases
    short* lb0 = LB + (w * 8) * 64;
    const int fsw = l16 & 7;                 // read-side swizzle (row&7)

    f32x4 acc[4][4];
    #pragma unroll
    for (int i = 0; i < 4; i++)
      #pragma unroll
      for (int j = 0; j < 4; j++) acc[i][j] = zero4;

    // STGA: full A tile (128 rows) = 2 loads/thread.
    // STGB: one B half (128 rows)  = 2 loads/thread.
    auto STGA = [&](int kt) {
      if (kt >= 12) kt -= 2;  // tail: idempotent re-stage (same buf, same data)
      const int buf = kt & 1;
      const short* g = ag0 + (size_t)kt * 64;
      short* lb = la0 + buf * (128 * 64);
      async_load16(g, lb);
      async_load16(g + (size_t)64 * K, lb + 64 * 64);
    };
    auto STGB = [&](int h, int kt) {
      if (kt >= 12) kt -= 2;
      const int buf = kt & 1;
      const short* g = bg0 + (size_t)h * 128 * K + (size_t)kt * 64;
      short* lb = lb0 + buf * (256 * 64) + h * (128 * 64);
      async_load16(g, lb);
      async_load16(g + (size_t)64 * K, lb + 64 * 64);
    };

    short8 af[4][2];   // A frags: 4 i x 2 kb (whole K-tile)
    short8 bfr[2][2];  // B frags: current JH pair, 2 j x 2 kb

#define LDA_(BUF)                                                            \
  _Pragma("unroll") for (int i = 0; i < 4; i++)                              \
    _Pragma("unroll") for (int kb = 0; kb < 2; kb++)                         \
      af[i][kb] = *(const short8*)&LA[(BUF)*8192 +                           \
          (wr * 64 + i * 16 + l16) * 64 + (((kb * 4 + quad) ^ fsw) * 8)];
#define LDB_(BUF, JH)                                                        \
  _Pragma("unroll") for (int j = 0; j < 2; j++)                              \
    _Pragma("unroll") for (int kb = 0; kb < 2; kb++)                         \
      bfr[j][kb] = *(const short8*)&LB[(BUF)*16384 +                         \
          (wc * 64 + (JH)*32 + j * 16 + l16) * 64 +                          \
          (((kb * 4 + quad) ^ fsw) * 8)];
#define MM_(JH)                                                              \
  __builtin_amdgcn_s_setprio(1);                                             \
  _Pragma("unroll") for (int i = 0; i < 4; i++)                              \
    _Pragma("unroll") for (int j = 0; j < 2; j++) {                          \
      acc[i][(JH)*2 + j] = MFMA16(af[i][0], bfr[j][0], acc[i][(JH)*2 + j]);  \
      acc[i][(JH)*2 + j] = MFMA16(af[i][1], bfr[j][1], acc[i][(JH)*2 + j]);  \
    }                                                                        \
  __builtin_amdgcn_s_setprio(0);

    // ---- prologue: tile 0 (6 loads); drain; bar ----
    STGA(0); STGB(0, 0); STGB(1, 0);
    VMW(0); KBAR();

    // ---- main loop: 12 K-tiles x 2 phases ----
    // alpha: LDA(12 reads w/ LDB-JH0) + stage A(t+1),B-lo(t+1); MM(JH0)
    // beta : LDB-JH1 (4 reads) + stage B-hi(t+1); MM(JH1); VMW(0)
    // Staging into buf (t+1)&1 is safe: its tenant t-1 was last read in
    // t-1.beta, sealed by the barrier before t.alpha issues.
    #pragma unroll 1
    for (int t = 0; t < 12; ++t) {
      const int c = t & 1;
      // alpha
      LDA_(c); LDB_(c, 0); STGA(t + 1); STGB(0, t + 1);
      KBAR(); MM_(0); KBAR();
      // beta
      LDB_(c, 1); STGB(1, t + 1);
      KBAR(); MM_(1); VMW(0); KBAR();
    }
#undef LDA_
#undef LDB_
#undef MM_

    // ---- epilogue ----
    if (z == 0) {
      #pragma unroll
      for (int I = 0; I < 4; I++)
        #pragma unroll
        for (int J = 0; J < 4; J++) {
          const int col = n0 + wc * 64 + J * 16 + l16;
          const float bv = bias[col];
          #pragma unroll
          for (int r = 0; r < 4; r++) {
            const int g = m0 + wr * 64 + I * 16 + quad * 4 + r;
            kp[(size_t)g * 768 + col] = f2bf(acc[I][J][r] + bv);
          }
        }
    } else {
      const int hh = (n0 >> 6) + wc;           // wave-constant head
      const int bs_ = (m0 >> 6) + wr;          // wave-constant sentence
      #pragma unroll
      for (int I = 0; I < 4; I++) {
        const int t0 = I * 16 + quad * 4;      // token base within sentence
        #pragma unroll
        for (int J = 0; J < 4; J++) {
          const int dd = J * 16 + l16;
          const float bv = bias[hh * 64 + dd];
          __align__(8) short tmp[4];
          #pragma unroll
          for (int r = 0; r < 4; r++) tmp[r] = f2bf(acc[I][J][r] + bv);
          *(short4v*)&vT[(((size_t)bs_ * 12 + hh) * 64 + dd) * 64 + t0] =
              *(short4v*)tmp;
        }
      }
    }
    return;
  }

  // ================= small branch (gemm_small body, BK=32) =================
  {
    const int id = blockIdx.x + 128 * blockIdx.y;  // 0..383
    if (id >= 108) return;
    short* As = smem;               // [128*32]
    short* Bs = smem + 128 * 32;    // [128*32]
    const int qmode = (id < 96);
    const int r = qmode ? id : (id - 96);
    const int bx = qmode ? (r % 8) : (r % 2);
    const int by = qmode ? (r / 8) : (r / 2);
    const short* A = qmode ? qbf : kvb;
    const short* WT = qmode ? (WT6 + 0 * WELEM) : (WT6 + 4 * WELEM);

    const int wm = (w >> 1) * 64, wn = (w & 1) * 64;  // valid for tid<256
    const int m0 = bx * 128, n0 = by * 128;
    const int grow = w * 32 + (lane >> 2);
    const int kc = (lane & 3) * 8;
    const short* ag = A + (size_t)(m0 + grow) * K + kc;
    const short* bg = WT + (size_t)(n0 + grow) * K + kc;
    short* al = &As[(w * 32) * 32];
    short* bl = &Bs[(w * 32) * 32];

    f32x4 acc[4][4];
    #pragma unroll
    for (int i = 0; i < 4; i++)
      #pragma unroll
      for (int j = 0; j < 4; j++) acc[i][j] = zero4;

    for (int k0 = 0; k0 < K; k0 += 32) {
      __syncthreads();
      if (tid < 256) {
        async_load16(ag, al);
        async_load16(ag + (size_t)16 * K, al + 16 * 32);
        async_load16(bg, bl);
        async_load16(bg + (size_t)16 * K, bl + 16 * 32);
      }
      ag += 32;
      bg += 32;
      __syncthreads();
      if (tid < 256) {
        short8 af[4], bf[4];
        #pragma unroll
        for (int i = 0; i < 4; i++)
          af[i] = *(short8*)&As[(wm + i * 16 + l16) * 32 + quad * 8];
        #pragma unroll
        for (int j = 0; j < 4; j++)
          bf[j] = *(short8*)&Bs[(wn + j * 16 + l16) * 32 + quad * 8];
        #pragma unroll
        for (int i = 0; i < 4; i++)
          #pragma unroll
          for (int j = 0; j < 4; j++)
            acc[i][j] = MFMA16(af[i], bf[j], acc[i][j]);
      }
    }
    if (tid >= 256) return;

    #pragma unroll
    for (int i = 0; i < 4; i++) {
      #pragma unroll
      for (int j = 0; j < 4; j++) {
        const int col = n0 + wn + j * 16 + l16;
        const float bv = qmode ? ((col < 768) ? wq_b[col] : sq_b[col - 768])
                               : sk_b[col];
        #pragma unroll
        for (int r4 = 0; r4 < 4; r4++) {
          const int g = m0 + wm + i * 16 + quad * 4 + r4;
          const float v = acc[i][j][r4] + bv;
          if (qmode) {
            if (col < 768) qp[(size_t)g * 768 + col] = f2bf(v * 0.125f);
            else sqp[(size_t)g * 768 + (col - 768)] = v;
          } else {
            skp[(size_t)g * 768 + col] = v;
          }
        }
      }
    }
  }
}

// ---------------------------------------------------------------------------
// blocks [0,3072): word-level attention per (b, s, h):
//   S = Qs Kt (Q pre-scaled by 1/8); maskless-max softmax; O = P V -> wh
// blocks [3072,4096): sentence-attention probabilities per (b, q)
// ---------------------------------------------------------------------------
__global__ __launch_bounds__(256)
void wattn_sp(const short* __restrict__ q_proj, const short* __restrict__ k_proj,
              const short* __restrict__ vT, const int* __restrict__ word_mask,
              const float* __restrict__ sq, const float* __restrict__ sk,
              const int* __restrict__ sent_mask, short* __restrict__ wh,
              float* __restrict__ probs2) {
  __shared__ __align__(16) short KVs[128 * 72];  // K rows 0-63, Vt rows 64-127; O overlay
  __shared__ __align__(16) short Ps[128 * 72];   // P bf16
  const int bid = blockIdx.x;
  const int tid = threadIdx.x;

  if (bid >= 3072) {
    // ---------------- sentence probs ----------------
    float* sc = (float*)KVs;  // 12*33 floats
    const int bq = bid - 3072;
    const int b = bq >> 7, q = bq & 127;
    for (int p = tid; p < 384; p += 256) {
      const int hh = p >> 5, ss = p & 31;
      const float4* a = (const float4*)(sq + ((size_t)(b * 128 + q)) * 768 + hh * 64);
      const float4* c = (const float4*)(sk + ((size_t)(b * 32 + ss)) * 768 + hh * 64);
      float d = 0.f;
      #pragma unroll
      for (int i = 0; i < 16; i++) {
        const float4 av = a[i], cv = c[i];
        d += av.x * cv.x + av.y * cv.y + av.z * cv.z + av.w * cv.w;
      }
      d = d * 0.125f + (1.0f - (float)sent_mask[bq * 32 + ss]) * -10000.0f;
      sc[hh * 33 + ss] = d;
    }
    __syncthreads();
    if (tid < 12) {
      float mx = -3.0e38f;
      for (int ss = 0; ss < 32; ss++) mx = fmaxf(mx, sc[tid * 33 + ss]);
      float sum = 0.f;
      for (int ss = 0; ss < 32; ss++) {
        const float e = __expf(sc[tid * 33 + ss] - mx);
        sc[tid * 33 + ss] = e;
        sum += e;
      }
      const float inv = 1.0f / sum;
      for (int ss = 0; ss < 32; ss++) sc[tid * 33 + ss] *= inv;
    }
    __syncthreads();
    for (int p = tid; p < 384; p += 256) {
      const int hh = p >> 5, ss = p & 31;
      probs2[((size_t)bq * 12 + hh) * 32 + ss] = sc[hh * 33 + ss];
    }
    return;
  }

  // ---------------- word attention ----------------
  short* Ks = KVs;
  short* Vs = KVs + 64 * 72;
  short* Os = KVs;
  const int h = bid % 12, s = (bid / 12) % 32, b = bid / (12 * 32);
  const int w = tid >> 6, lane = tid & 63, quad = lane >> 4, l16 = lane & 15;
  const f32x4 zero4 = {0.f, 0.f, 0.f, 0.f};

  // ---- stage K (tid<128) and Vt (tid>=128): 8 lanes/row x 16B ----
  {
    const int t2 = tid & 127;
    const int row8 = t2 >> 3;      // 0..15
    const int c8 = (t2 & 7) * 8;   // short offset within 64
    if (tid < 128) {
      const short* src = k_proj + ((size_t)((b * 32 + s) * 64)) * 768 + h * 64 + c8;
      #pragma unroll
      for (int i = 0; i < 4; i++) {
        const int r = row8 + i * 16;
        *(short8*)&Ks[r * 72 + c8] = *(const short8*)(src + (size_t)r * 768);
      }
    } else {
      const short* src = vT + ((size_t)((b * 32 + s) * 12 + h)) * 4096 + c8;
      #pragma unroll
      for (int i = 0; i < 4; i++) {
        const int r = row8 + i * 16;
        *(short8*)&Vs[r * 72 + c8] = *(const short8*)(src + (size_t)r * 64);
      }
    }
  }
  __syncthreads();

  // ---- S = Qs Kt ----
  f32x4 sac[2][4];
  #pragma unroll
  for (int i = 0; i < 2; i++)
    #pragma unroll
    for (int j = 0; j < 4; j++) sac[i][j] = zero4;
  {
    short8 aq[2][2], bk[4][2];
    #pragma unroll
    for (int i = 0; i < 2; i++)
      #pragma unroll
      for (int kb = 0; kb < 2; kb++)
        aq[i][kb] = *(const short8*)(q_proj +
            ((size_t)(b * 128 + w * 32 + i * 16 + l16)) * 768 + h * 64 + kb * 32 + quad * 8);
    #pragma unroll
    for (int j = 0; j < 4; j++)
      #pragma unroll
      for (int kb = 0; kb < 2; kb++)
        bk[j][kb] = *(short8*)&Ks[(j * 16 + l16) * 72 + kb * 32 + quad * 8];
    #pragma unroll
    for (int i = 0; i < 2; i++)
      #pragma unroll
      for (int j = 0; j < 4; j++) {
        sac[i][j] = MFMA16(aq[i][0], bk[j][0], sac[i][j]);
        sac[i][j] = MFMA16(aq[i][1], bk[j][1], sac[i][j]);
      }
  }

  // ---- maskless-max softmax (|S|<~5 bounded; masked -> exp==0 exactly) ----
  {
    float wmv[4];
    const int* wmp = word_mask + (b * 32 + s) * 64;
    #pragma unroll
    for (int j = 0; j < 4; j++)
      wmv[j] = (1.0f - (float)wmp[j * 16 + l16]) * -10000.0f;
    #pragma unroll
    for (int i = 0; i < 2; i++) {
      #pragma unroll
      for (int r = 0; r < 4; r++) {
        float vv[4];
        float sum = 0.f;
        #pragma unroll
        for (int j = 0; j < 4; j++) {
          vv[j] = __expf(sac[i][j][r] + wmv[j]);
          sum += vv[j];
        }
        sum += __shfl_xor(sum, 1);
        sum += __shfl_xor(sum, 2);
        sum += __shfl_xor(sum, 4);
        sum += __shfl_xor(sum, 8);
        const float inv = 1.0f / sum;
        const int row = w * 32 + i * 16 + quad * 4 + r;
        #pragma unroll
        for (int j = 0; j < 4; j++)
          Ps[row * 72 + j * 16 + l16] = f2bf(vv[j] * inv);
      }
    }
  }
  __syncthreads();

  // ---- O = P V ----
  f32x4 oac[2][4];
  #pragma unroll
  for (int i = 0; i < 2; i++)
    #pragma unroll
    for (int j = 0; j < 4; j++) oac[i][j] = zero4;
  {
    short8 ap[2][2], bv[4][2];
    #pragma unroll
    for (int i = 0; i < 2; i++)
      #pragma unroll
      for (int kb = 0; kb < 2; kb++)
        ap[i][kb] = *(short8*)&Ps[(w * 32 + i * 16 + l16) * 72 + kb * 32 + quad * 8];
    #pragma unroll
    for (int j = 0; j < 4; j++)
      #pragma unroll
      for (int kb = 0; kb < 2; kb++)
        bv[j][kb] = *(short8*)&Vs[(j * 16 + l16) * 72 + kb * 32 + quad * 8];
    #pragma unroll
    for (int i = 0; i < 2; i++)
      #pragma unroll
      for (int j = 0; j < 4; j++) {
        oac[i][j] = MFMA16(ap[i][0], bv[j][0], oac[i][j]);
        oac[i][j] = MFMA16(ap[i][1], bv[j][1], oac[i][j]);
      }
  }
  __syncthreads();  // K/V reads complete before O overlay write
  #pragma unroll
  for (int i = 0; i < 2; i++)
    #pragma unroll
    for (int j = 0; j < 4; j++)
      #pragma unroll
      for (int r = 0; r < 4; r++)
        Os[(w * 32 + i * 16 + quad * 4 + r) * 72 + j * 16 + l16] = f2bf(oac[i][j][r]);
  __syncthreads();

  // ---- wh store: 8 lanes/row x 16B -> 128B-contiguous segments ----
  {
    const int c8 = (tid & 7) * 8;
    #pragma unroll
    for (int i = 0; i < 4; i++) {
      const int row = i * 32 + (tid >> 3);
      short* dst = wh + (((size_t)(b * 128 + row)) * 32 + s) * 768 + h * 64;
      *(short8*)(dst + c8) = *(const short8*)&Os[row * 72 + c8];
    }
  }
}

// ---------------------------------------------------------------------------
// whc[h, bq, k] = sum_s probs2[bq,h,s] * wh[bq,s,k]   (bf16 out)
// ---------------------------------------------------------------------------
__global__ __launch_bounds__(256)
void whc_kernel(const short* __restrict__ wh, const float* __restrict__ probs2,
                short* __restrict__ whc) {
  __shared__ __align__(16) short whs[32 * 776];  // pad 768->776: conflict-free reads
  __shared__ float p2s[384];
  const int bq = blockIdx.x, tid = threadIdx.x;
  const short8* src = (const short8*)(wh + (size_t)bq * 24576);
  for (int t = tid; t < 3072; t += 256) {
    const int row = t / 96, c8 = (t % 96) * 8;
    *(short8*)&whs[row * 776 + c8] = src[t];
  }
  for (int p = tid; p < 384; p += 256) p2s[p] = probs2[(size_t)bq * 384 + p];
  __syncthreads();

  float acc[3][12];
  #pragma unroll
  for (int kk = 0; kk < 3; kk++)
    #pragma unroll
    for (int h = 0; h < 12; h++) acc[kk][h] = 0.f;

  for (int s = 0; s < 32; s++) {
    float p2r[12];
    #pragma unroll
    for (int h = 0; h < 12; h++) p2r[h] = p2s[h * 32 + s];
    #pragma unroll
    for (int kk = 0; kk < 3; kk++) {
      const float wv = bf2f(whs[s * 776 + kk * 256 + tid]);
      #pragma unroll
      for (int h = 0; h < 12; h++) acc[kk][h] += p2r[h] * wv;
    }
  }
  #pragma unroll
  for (int h = 0; h < 12; h++)
    #pragma unroll
    for (int kk = 0; kk < 3; kk++)
      whc[((size_t)h * 1024 + bq) * 768 + kk * 256 + tid] = f2bf(acc[kk][h]);
}

// ---------------------------------------------------------------------------
// outg: per-head GEMM  out[bq, h*64+d] = whc[h,bq,:] @ sv_w[:, h*64+d] + sv_b
// ---------------------------------------------------------------------------
__global__ __launch_bounds__(256)
void outg(const short* __restrict__ whc, const short* __restrict__ WTsv,
          const float* __restrict__ sv_b, float* __restrict__ out) {
  const int K = 768;
  __shared__ __align__(16) short As[128 * 32];
  __shared__ __align__(16) short Bs[64 * 32];
  const int tid = threadIdx.x;
  const int m0 = blockIdx.x * 128, h = blockIdx.y;
  const int w = tid >> 6, lane = tid & 63, quad = lane >> 4, l16 = lane & 15;
  const int wm = (w >> 1) * 64, wn = (w & 1) * 32;

  const int grow = w * 32 + (lane >> 2);
  const int kc = (lane & 3) * 8;
  const short* ag = whc + ((size_t)h * 1024 + m0 + grow) * K + kc;
  short* al = &As[(w * 32) * 32];
  const int growb = w * 16 + (lane >> 2);
  const short* bg = WTsv + (size_t)(h * 64 + growb) * K + kc;
  short* bl = &Bs[(w * 16) * 32];

  const f32x4 zero4 = {0.f, 0.f, 0.f, 0.f};
  f32x4 acc[4][2];
  #pragma unroll
  for (int i = 0; i < 4; i++)
    #pragma unroll
    for (int j = 0; j < 2; j++) acc[i][j] = zero4;

  for (int k0 = 0; k0 < K; k0 += 32) {
    __syncthreads();
    async_load16(ag, al);
    async_load16(ag + (size_t)16 * K, al + 16 * 32);
    async_load16(bg, bl);
    ag += 32;
    bg += 32;
    __syncthreads();
    short8 af[4], bf[2];
    #pragma unroll
    for (int i = 0; i < 4; i++)
      af[i] = *(short8*)&As[(wm + i * 16 + l16) * 32 + quad * 8];
    #pragma unroll
    for (int j = 0; j < 2; j++)
      bf[j] = *(short8*)&Bs[(wn + j * 16 + l16) * 32 + quad * 8];
    #pragma unroll
    for (int i = 0; i < 4; i++)
      #pragma unroll
      for (int j = 0; j < 2; j++)
        acc[i][j] = MFMA16(af[i], bf[j], acc[i][j]);
  }

  #pragma unroll
  for (int i = 0; i < 4; i++) {
    #pragma unroll
    for (int j = 0; j < 2; j++) {
      const int col = h * 64 + wn + j * 16 + l16;
      const float bv = sv_b[col];
      #pragma unroll
      for (int r = 0; r < 4; r++) {
        const int g = m0 + wm + i * 16 + quad * 4 + r;
        out[(size_t)g * 768 + col] = acc[i][j][r] + bv;
      }
    }
  }
}

// ---------------------------------------------------------------------------
extern "C" void kernel_launch(void* const* d_in, const int* in_sizes, int n_in,
                              void* d_out, int out_size, void* d_ws, size_t ws_size,
                              hipStream_t stream) {
  (void)in_sizes; (void)n_in; (void)out_size; (void)ws_size;
  const float* q_in      = (const float*)d_in[0];   // [8,128,768]
  const float* k_in      = (const float*)d_in[1];   // [8,32,64,768]
  const float* v_in      = (const float*)d_in[2];   // [8,32,64,768]
  const float* kvec      = (const float*)d_in[3];   // [8,32,768]
  const int*   word_mask = (const int*)d_in[4];     // [8,32,64]
  const int*   sent_mask = (const int*)d_in[5];     // [1024,32]
  const float* wq_w = (const float*)d_in[6],  *wq_b = (const float*)d_in[7];
  const float* wk_w = (const float*)d_in[8],  *wk_b = (const float*)d_in[9];
  const float* wv_w = (const float*)d_in[10], *wv_b = (const float*)d_in[11];
  const float* sq_w = (const float*)d_in[12], *sq_b = (const float*)d_in[13];
  const float* sk_w = (const float*)d_in[14], *sk_b = (const float*)d_in[15];
  const float* sv_w = (const float*)d_in[16], *sv_b = (const float*)d_in[17];
  float* out = (float*)d_out;

  const int WELEM = 768 * 768;

  static bool s_attr_done = false;
  if (!s_attr_done) {
    (void)hipFuncSetAttribute(reinterpret_cast<const void*>(&gemm_proj),
                              hipFuncAttributeMaxDynamicSharedMemorySize, 98304);
    s_attr_done = true;
  }

  char* ws = (char*)d_ws;
  size_t off = 0;
  auto alloc = [&](size_t bytes) -> void* {
    void* p = ws + off;
    off += (bytes + 255) & ~(size_t)255;
    return p;
  };
  short* WT  = (short*)alloc((size_t)6 * 768 * 768 * 2);   // wq,sq,wk,wv,sk,sv
  short* qbf = (short*)alloc((size_t)1024 * 768 * 2);
  short* kbf = (short*)alloc((size_t)16384 * 768 * 2);
  short* vbf = (short*)alloc((size_t)16384 * 768 * 2);
  short* kvb = (short*)alloc((size_t)256 * 768 * 2);
  short* qp  = (short*)alloc((size_t)1024 * 768 * 2);      // pre-scaled by 1/8
  short* kp  = (short*)alloc((size_t)16384 * 768 * 2);
  short* vT  = (short*)alloc((size_t)16384 * 768 * 2);     // [b,s,h,d,t]
  float* sqp = (float*)alloc((size_t)1024 * 768 * 4);
  float* skp = (float*)alloc((size_t)256 * 768 * 4);
  short* wh  = (short*)alloc((size_t)32768 * 768 * 2);     // 50.3 MB
  float* pr2 = (float*)alloc((size_t)1024 * 12 * 32 * 4);  //  1.6 MB
  short* whc = (short*)alloc((size_t)12 * 1024 * 768 * 2); // 18.9 MB [h,bq,k]

  // 1: weight transposes + activation converts
  prep<<<dim3(16224), 256, 0, stream>>>(wq_w, sq_w, wk_w, wv_w, sk_w, sv_w, WT,
                                        q_in, k_in, v_in, kvec, qbf, kbf, vbf, kvb);
  // 2: ALL projections (z<2: kv 128x256 2-phase bodies; z==2: q+sq,sk small)
  gemm_proj<<<dim3(128, 3, 3), 512, 98304, stream>>>(
      kbf, vbf, qbf, kvb, WT, wk_b, wv_b, wq_b, sq_b, sk_b,
      kp, vT, qp, sqp, skp);
  // 3: word attention (+ sentence probs in blocks >= 3072)
  wattn_sp<<<dim3(4096), 256, 0, stream>>>(qp, kp, vT, word_mask, sqp, skp,
                                           sent_mask, wh, pr2);
  // 4: sentence contraction over s (commutes with sv projection)
  whc_kernel<<<dim3(1024), 256, 0, stream>>>(wh, pr2, whc);
  // 5: per-head output GEMM -> out
  outg<<<dim3(8, 12), 256, 0, stream>>>(whc, WT + 5 * WELEM, sv_b, out);
}

// Round 7
// 319.481 us; speedup vs baseline: 1.0414x; 1.0414x over previous
//
#include <hip/hip_runtime.h>
#include <hip/hip_bf16.h>

// Problem constants: BS=8, Q=128, S1=32, S2=64, H=768, NH=12, DH=64.

typedef __attribute__((ext_vector_type(8))) short short8;
typedef __attribute__((ext_vector_type(4))) short short4v;
typedef __attribute__((ext_vector_type(4))) float f32x4;

__device__ __forceinline__ short f2bf(float f) {
  __hip_bfloat16 b = __float2bfloat16(f);
  return __builtin_bit_cast(short, b);
}
__device__ __forceinline__ float bf2f(short s) {
  __hip_bfloat16 b = __builtin_bit_cast(__hip_bfloat16, s);
  return __bfloat162float(b);
}

#define MFMA16(a, b, c) __builtin_amdgcn_mfma_f32_16x16x32_bf16((a), (b), (c), 0, 0, 0)

// async 16B/lane global->LDS (wave-uniform LDS base; HW adds lane*16)
__device__ __forceinline__ void async_load16(const void* g, void* l) {
  auto l3 = (__attribute__((address_space(3))) void*)(uintptr_t)(
      reinterpret_cast<uintptr_t>(l));
  auto g1 = (const __attribute__((address_space(1))) void*)g;
  __builtin_amdgcn_global_load_lds(g1, l3, 16, 0, 0);
}

// raw barrier (no implicit vmcnt(0) drain) + compiler memory fence
#define KBAR()                                      \
  do {                                              \
    asm volatile("" ::: "memory");                  \
    __builtin_amdgcn_s_barrier();                   \
    asm volatile("" ::: "memory");                  \
  } while (0)
#define VMW(N) asm volatile("s_waitcnt vmcnt(" #N ")" ::: "memory")

// ---------------------------------------------------------------------------
// prep: blocks [0,3456) = 6 weight transposes (fp32 -> bf16, WT[n][k]);
//       blocks [3456,5504) = grid-strided fp32->bf16 convert of q/k/v/kvec
//       (2048 cvt blocks per Guideline 11 instead of 12768 one-shot blocks).
// ---------------------------------------------------------------------------
__global__ __launch_bounds__(256)
void prep(const float* __restrict__ w0, const float* __restrict__ w1,
          const float* __restrict__ w2, const float* __restrict__ w3,
          const float* __restrict__ w4, const float* __restrict__ w5,
          short* __restrict__ WT,
          const float* __restrict__ q_in, const float* __restrict__ k_in,
          const float* __restrict__ v_in, const float* __restrict__ kvec,
          short* __restrict__ qbf, short* __restrict__ kbf,
          short* __restrict__ vbf, short* __restrict__ kvb) {
  const int id = blockIdx.x;
  const int tid = threadIdx.x;
  if (id < 3456) {
    __shared__ float tile[32][33];
    const int zz = id / 576, r = id % 576;
    const float* W = (zz == 0) ? w0 : (zz == 1) ? w1 : (zz == 2) ? w2
                   : (zz == 3) ? w3 : (zz == 4) ? w4 : w5;
    short* WTo = WT + (size_t)zz * 768 * 768;
    const int bx = (r % 24) * 32, by = (r / 24) * 32;
    const int tx = tid & 31, ty = tid >> 5;  // 32 x 8
    #pragma unroll
    for (int i = 0; i < 32; i += 8)
      tile[ty + i][tx] = W[(size_t)(by + ty + i) * 768 + bx + tx];
    __syncthreads();
    #pragma unroll
    for (int i = 0; i < 32; i += 8)
      WTo[(size_t)(bx + ty + i) * 768 + by + tx] = f2bf(tile[tx][ty + i]);
    return;
  }
  // ---- cvt: short8 units: q 98304 | k 1572864 | v 1572864 | kvec 24576 ----
  // total units = 3268608; grid-stride over 2048 blocks x 256 threads.
  for (int i = (id - 3456) * 256 + tid; i < 3268608; i += 2048 * 256) {
    const float* src;
    short* dst;
    int idx;
    if (i < 98304)        { src = q_in; dst = qbf; idx = i; }
    else if (i < 1671168) { src = k_in; dst = kbf; idx = i - 98304; }
    else if (i < 3244032) { src = v_in; dst = vbf; idx = i - 1671168; }
    else                  { src = kvec; dst = kvb; idx = i - 3244032; }
    const float4* s = (const float4*)src + (size_t)idx * 2;
    const float4 a = s[0], b = s[1];
    __align__(16) short tmp[8] = {f2bf(a.x), f2bf(a.y), f2bf(a.z), f2bf(a.w),
                                  f2bf(b.x), f2bf(b.y), f2bf(b.z), f2bf(b.w)};
    *((short8*)dst + idx) = *(short8*)tmp;
  }
}

// ---------------------------------------------------------------------------
// All projections, one launch, grid (64, 3, 3), 512 threads, 128 KiB dyn LDS:
//   z<2 : kv GEMM, 256x256 tile, BK=64, 8-phase schedule (R4-proven body:
//         fine staging — one half-tile = 2 global_load_lds per phase at
//         earliest-legal slots, VMW(4) at P4/P8 with 2 phases of slack;
//         load-once B fragments cut LDS reads 32->24 per K-tile/wave).
//   z==2: EXACT gemm_small body (BK=32, 256 active threads; threads 256-511
//         only participate in barriers). 108 active blocks.
// ---------------------------------------------------------------------------
__global__ __launch_bounds__(512, 2)
void gemm_proj(const short* __restrict__ kbf, const short* __restrict__ vbf,
               const short* __restrict__ qbf, const short* __restrict__ kvb,
               const short* __restrict__ WT6,
               const float* __restrict__ wk_b, const float* __restrict__ wv_b,
               const float* __restrict__ wq_b, const float* __restrict__ sq_b,
               const float* __restrict__ sk_b,
               short* __restrict__ kp, short* __restrict__ vT,
               short* __restrict__ qp, float* __restrict__ sqp,
               float* __restrict__ skp) {
  const int K = 768, WELEM = 768 * 768;
  extern __shared__ __align__(16) char smem_c[];
  short* smem = (short*)smem_c;
  const int tid = threadIdx.x;
  const int w = tid >> 6, lane = tid & 63, quad = lane >> 4, l16 = lane & 15;
  const f32x4 zero4 = {0.f, 0.f, 0.f, 0.f};

  if (blockIdx.z < 2) {
    // ================= kv branch: 256^2 tile, 8-phase pipeline =============
    short* LA = smem;                  // [2 buf][256 rows][64 cols] bf16
    short* LB = smem + 2 * 256 * 64;   // [2 buf][256 rows][64 cols] bf16
    const int z = blockIdx.z;
    const short* Ag = z ? vbf : kbf;
    const short* Bg = z ? (WT6 + 3 * WELEM) : (WT6 + 2 * WELEM);
    const float* bias = z ? wv_b : wk_b;
    const int m0 = blockIdx.x * 256, n0 = blockIdx.y * 256;
    const int wr = w >> 2, wc = w & 3;  // 2 x 4 wave grid; wave tile 128x64

    // staging geometry: thread covers row (w*8 + lane/8), swizzled chunk
    // LDS[r][c] = G[r][c ^ (r&7)]  (chunk = 8 bf16 = 16B)
    const int srow = lane >> 3;              // 0..7
    const int schk = (lane & 7) ^ srow;      // pre-swizzled global chunk
    const short* ag0 = Ag + (size_t)(m0 + w * 8 + srow) * K + schk * 8;
    const short* bg0 = Bg + (size_t)(n0 + w * 8 + srow) * K + schk * 8;
    short* la0 = LA + (w * 8) * 64;          // wave-uniform LDS bases
    short* lb0 = LB + (w * 8) * 64;
    const int fsw = l16 & 7;                 // read-side swizzle (row&7)

    f32x4 acc[8][4];
    #pragma unroll
    for (int i = 0; i < 8; i++)
      #pragma unroll
      for (int j = 0; j < 4; j++) acc[i][j] = zero4;

    // stage one half-tile (128 rows x 64 cols) = 2 x global_load_lds / thread
    // op: 0=A 1=B ; h: row-half ; kt: K-tile index (0..11)
    auto STG1 = [&](int op, int h, int kt) {
      if (kt >= 12) kt -= 2;  // tail: idempotent re-stage (same buf, same data)
      const int buf = kt & 1;
      const short* g = (op ? bg0 : ag0) + (size_t)h * 128 * K + (size_t)kt * 64;
      short* lb = (op ? lb0 : la0) + buf * 16384 + h * (128 * 64);
      async_load16(g, lb);
      async_load16(g + (size_t)64 * K, lb + 64 * 64);
    };

    short8 af[4][2];        // A frags of current IH: 4 i x 2 kb
    short8 bfr[2][2][2];    // B frags load-once: [JH][j][kb]

#define LDA_(BUF, IH)                                                        \
  _Pragma("unroll") for (int i = 0; i < 4; i++)                              \
    _Pragma("unroll") for (int kb = 0; kb < 2; kb++)                         \
      af[i][kb] = *(const short8*)&LA[(BUF)*16384 +                          \
          (wr * 128 + (IH)*64 + i * 16 + l16) * 64 +                         \
          (((kb * 4 + quad) ^ fsw) * 8)];
#define LDB_(BUF, JH)                                                        \
  _Pragma("unroll") for (int j = 0; j < 2; j++)                              \
    _Pragma("unroll") for (int kb = 0; kb < 2; kb++)                         \
      bfr[JH][j][kb] = *(const short8*)&LB[(BUF)*16384 +                     \
          (wc * 64 + (JH)*32 + j * 16 + l16) * 64 +                          \
          (((kb * 4 + quad) ^ fsw) * 8)];
#define MM_(IH, JH)                                                          \
  __builtin_amdgcn_s_setprio(1);                                             \
  _Pragma("unroll") for (int i = 0; i < 4; i++)                              \
    _Pragma("unroll") for (int j = 0; j < 2; j++) {                          \
      acc[(IH)*4 + i][(JH)*2 + j] =                                          \
          MFMA16(af[i][0], bfr[JH][j][0], acc[(IH)*4 + i][(JH)*2 + j]);      \
      acc[(IH)*4 + i][(JH)*2 + j] =                                          \
          MFMA16(af[i][1], bfr[JH][j][1], acc[(IH)*4 + i][(JH)*2 + j]);      \
    }                                                                        \
  __builtin_amdgcn_s_setprio(0);

    // ---- prologue: tile0 (8 loads) + B(1) (4 loads); drain tile0 ----
    STG1(0, 0, 0); STG1(0, 1, 0); STG1(1, 0, 0); STG1(1, 1, 0);
    STG1(1, 0, 1); STG1(1, 1, 1);
    VMW(4);   // tile 0 landed; B(1) in flight (steady-state queue invariant)
    KBAR();

    // ---- main loop: 12 K-tiles = 6 iterations x 8 phases ----
    // e=2it (buf0, computed P1-P4), o=2it+1 (buf1, P5-P8), e2=e+2, o2=o+2.
    // Reads (load-once B): LDA P1/P3/P5/P7, LDB P1/P2/P5/P6.
    // Quadrant order per K-tile (snake): (0,0)(0,1)(1,1)(1,0).
    // Stage plan (1 half/phase, earliest legal):
    //   P1: A-lo(o)  P2: A-hi(o)  P3: B-lo(e2)  P4: B-hi(e2)
    //   P5: A-lo(e2) P6: A-hi(e2) P7: B-lo(o2)  P8: B-hi(o2)
    // VMW(4)@P4 drains B(o)@P7'/P8' + A(o)@P1/P2  (youngest slack 2 phases)
    // VMW(4)@P8 drains B(e2)@P3/P4 + A(e2)@P5/P6  (youngest slack 2 phases)
    #pragma unroll 1
    for (int it = 0; it < 6; ++it) {
      const int o = 2 * it + 1, e2 = 2 * it + 2, o2 = 2 * it + 3;
      // P1
      LDA_(0, 0); LDB_(0, 0); STG1(0, 0, o); KBAR(); MM_(0, 0); KBAR();
      // P2
      LDB_(0, 1); STG1(0, 1, o); KBAR(); MM_(0, 1); KBAR();
      // P3
      LDA_(0, 1); STG1(1, 0, e2); KBAR(); MM_(1, 1); KBAR();
      // P4
      STG1(1, 1, e2); KBAR(); MM_(1, 0); VMW(4); KBAR();
      // P5
      LDA_(1, 0); LDB_(1, 0); STG1(0, 0, e2); KBAR(); MM_(0, 0); KBAR();
      // P6
      LDB_(1, 1); STG1(0, 1, e2); KBAR(); MM_(0, 1); KBAR();
      // P7
      LDA_(1, 1); STG1(1, 0, o2); KBAR(); MM_(1, 1); KBAR();
      // P8
      STG1(1, 1, o2); KBAR(); MM_(1, 0); VMW(4); KBAR();
    }
#undef LDA_
#undef LDB_
#undef MM_
    VMW(0);  // drain trailing idempotent stages before epilogue/endpgm

    // ---- epilogue ----
    if (z == 0) {
      #pragma unroll
      for (int I = 0; I < 8; I++)
        #pragma unroll
        for (int J = 0; J < 4; J++) {
          const int col = n0 + wc * 64 + J * 16 + l16;
          const float bv = bias[col];
          #pragma unroll
          for (int r = 0; r < 4; r++) {
            const int g = m0 + wr * 128 + I * 16 + quad * 4 + r;
            kp[(size_t)g * 768 + col] = f2bf(acc[I][J][r] + bv);
          }
        }
    } else {
      const int hh = (n0 >> 6) + wc;           // wave-constant head
      #pragma unroll
      for (int I = 0; I < 8; I++) {
        const int bs_ = (m0 >> 6) + wr * 2 + (I >> 2);  // global sentence
        const int t0 = (I & 3) * 16 + quad * 4;         // token base
        #pragma unroll
        for (int J = 0; J < 4; J++) {
          const int dd = J * 16 + l16;
          const float bv = bias[hh * 64 + dd];
          __align__(8) short tmp[4];
          #pragma unroll
          for (int r = 0; r < 4; r++) tmp[r] = f2bf(acc[I][J][r] + bv);
          *(short4v*)&vT[(((size_t)bs_ * 12 + hh) * 64 + dd) * 64 + t0] =
              *(short4v*)tmp;
        }
      }
    }
    return;
  }

  // ================= small branch (gemm_small body, BK=32) =================
  {
    const int id = blockIdx.x + 64 * blockIdx.y;  // 0..191
    if (id >= 108) return;
    short* As = smem;               // [128*32]
    short* Bs = smem + 128 * 32;    // [128*32]
    const int qmode = (id < 96);
    const int r = qmode ? id : (id - 96);
    const int bx = qmode ? (r % 8) : (r % 2);
    const int by = qmode ? (r / 8) : (r / 2);
    const short* A = qmode ? qbf : kvb;
    const short* WT = qmode ? (WT6 + 0 * WELEM) : (WT6 + 4 * WELEM);

    const int wm = (w >> 1) * 64, wn = (w & 1) * 64;  // valid for tid<256
    const int m0 = bx * 128, n0 = by * 128;
    const int grow = w * 32 + (lane >> 2);
    const int kc = (lane & 3) * 8;
    const short* ag = A + (size_t)(m0 + grow) * K + kc;
    const short* bg = WT + (size_t)(n0 + grow) * K + kc;
    short* al = &As[(w * 32) * 32];
    short* bl = &Bs[(w * 32) * 32];

    f32x4 acc[4][4];
    #pragma unroll
    for (int i = 0; i < 4; i++)
      #pragma unroll
      for (int j = 0; j < 4; j++) acc[i][j] = zero4;

    for (int k0 = 0; k0 < K; k0 += 32) {
      __syncthreads();
      if (tid < 256) {
        async_load16(ag, al);
        async_load16(ag + (size_t)16 * K, al + 16 * 32);
        async_load16(bg, bl);
        async_load16(bg + (size_t)16 * K, bl + 16 * 32);
      }
      ag += 32;
      bg += 32;
      __syncthreads();
      if (tid < 256) {
        short8 af[4], bf[4];
        #pragma unroll
        for (int i = 0; i < 4; i++)
          af[i] = *(short8*)&As[(wm + i * 16 + l16) * 32 + quad * 8];
        #pragma unroll
        for (int j = 0; j < 4; j++)
          bf[j] = *(short8*)&Bs[(wn + j * 16 + l16) * 32 + quad * 8];
        #pragma unroll
        for (int i = 0; i < 4; i++)
          #pragma unroll
          for (int j = 0; j < 4; j++)
            acc[i][j] = MFMA16(af[i], bf[j], acc[i][j]);
      }
    }
    if (tid >= 256) return;

    #pragma unroll
    for (int i = 0; i < 4; i++) {
      #pragma unroll
      for (int j = 0; j < 4; j++) {
        const int col = n0 + wn + j * 16 + l16;
        const float bv = qmode ? ((col < 768) ? wq_b[col] : sq_b[col - 768])
                               : sk_b[col];
        #pragma unroll
        for (int r4 = 0; r4 < 4; r4++) {
          const int g = m0 + wm + i * 16 + quad * 4 + r4;
          const float v = acc[i][j][r4] + bv;
          if (qmode) {
            if (col < 768) qp[(size_t)g * 768 + col] = f2bf(v * 0.125f);
            else sqp[(size_t)g * 768 + (col - 768)] = v;
          } else {
            skp[(size_t)g * 768 + col] = v;
          }
        }
      }
    }
  }
}

// ---------------------------------------------------------------------------
// blocks [0,3072): word-level attention per (b, s, h):
//   S = Qs Kt (Q pre-scaled by 1/8); maskless-max softmax; O = P V -> wh
// blocks [3072,4096): sentence-attention probabilities per (b, q)
// ---------------------------------------------------------------------------
__global__ __launch_bounds__(256)
void wattn_sp(const short* __restrict__ q_proj, const short* __restrict__ k_proj,
              const short* __restrict__ vT, const int* __restrict__ word_mask,
              const float* __restrict__ sq, const float* __restrict__ sk,
              const int* __restrict__ sent_mask, short* __restrict__ wh,
              float* __restrict__ probs2) {
  __shared__ __align__(16) short KVs[128 * 72];  // K rows 0-63, Vt rows 64-127; O overlay
  __shared__ __align__(16) short Ps[128 * 72];   // P bf16
  const int bid = blockIdx.x;
  const int tid = threadIdx.x;

  if (bid >= 3072) {
    // ---------------- sentence probs ----------------
    float* sc = (float*)KVs;  // 12*33 floats
    const int bq = bid - 3072;
    const int b = bq >> 7, q = bq & 127;
    for (int p = tid; p < 384; p += 256) {
      const int hh = p >> 5, ss = p & 31;
      const float4* a = (const float4*)(sq + ((size_t)(b * 128 + q)) * 768 + hh * 64);
      const float4* c = (const float4*)(sk + ((size_t)(b * 32 + ss)) * 768 + hh * 64);
      float d = 0.f;
      #pragma unroll
      for (int i = 0; i < 16; i++) {
        const float4 av = a[i], cv = c[i];
        d += av.x * cv.x + av.y * cv.y + av.z * cv.z + av.w * cv.w;
      }
      d = d * 0.125f + (1.0f - (float)sent_mask[bq * 32 + ss]) * -10000.0f;
      sc[hh * 33 + ss] = d;
    }
    __syncthreads();
    if (tid < 12) {
      float mx = -3.0e38f;
      for (int ss = 0; ss < 32; ss++) mx = fmaxf(mx, sc[tid * 33 + ss]);
      float sum = 0.f;
      for (int ss = 0; ss < 32; ss++) {
        const float e = __expf(sc[tid * 33 + ss] - mx);
        sc[tid * 33 + ss] = e;
        sum += e;
      }
      const float inv = 1.0f / sum;
      for (int ss = 0; ss < 32; ss++) sc[tid * 33 + ss] *= inv;
    }
    __syncthreads();
    for (int p = tid; p < 384; p += 256) {
      const int hh = p >> 5, ss = p & 31;
      probs2[((size_t)bq * 12 + hh) * 32 + ss] = sc[hh * 33 + ss];
    }
    return;
  }

  // ---------------- word attention ----------------
  short* Ks = KVs;
  short* Vs = KVs + 64 * 72;
  short* Os = KVs;
  const int h = bid % 12, s = (bid / 12) % 32, b = bid / (12 * 32);
  const int w = tid >> 6, lane = tid & 63, quad = lane >> 4, l16 = lane & 15;
  const f32x4 zero4 = {0.f, 0.f, 0.f, 0.f};

  // ---- stage K (tid<128) and Vt (tid>=128): 8 lanes/row x 16B ----
  {
    const int t2 = tid & 127;
    const int row8 = t2 >> 3;      // 0..15
    const int c8 = (t2 & 7) * 8;   // short offset within 64
    if (tid < 128) {
      const short* src = k_proj + ((size_t)((b * 32 + s) * 64)) * 768 + h * 64 + c8;
      #pragma unroll
      for (int i = 0; i < 4; i++) {
        const int r = row8 + i * 16;
        *(short8*)&Ks[r * 72 + c8] = *(const short8*)(src + (size_t)r * 768);
      }
    } else {
      const short* src = vT + ((size_t)((b * 32 + s) * 12 + h)) * 4096 + c8;
      #pragma unroll
      for (int i = 0; i < 4; i++) {
        const int r = row8 + i * 16;
        *(short8*)&Vs[r * 72 + c8] = *(const short8*)(src + (size_t)r * 64);
      }
    }
  }
  __syncthreads();

  // ---- S = Qs Kt ----
  f32x4 sac[2][4];
  #pragma unroll
  for (int i = 0; i < 2; i++)
    #pragma unroll
    for (int j = 0; j < 4; j++) sac[i][j] = zero4;
  {
    short8 aq[2][2], bk[4][2];
    #pragma unroll
    for (int i = 0; i < 2; i++)
      #pragma unroll
      for (int kb = 0; kb < 2; kb++)
        aq[i][kb] = *(const short8*)(q_proj +
            ((size_t)(b * 128 + w * 32 + i * 16 + l16)) * 768 + h * 64 + kb * 32 + quad * 8);
    #pragma unroll
    for (int j = 0; j < 4; j++)
      #pragma unroll
      for (int kb = 0; kb < 2; kb++)
        bk[j][kb] = *(short8*)&Ks[(j * 16 + l16) * 72 + kb * 32 + quad * 8];
    #pragma unroll
    for (int i = 0; i < 2; i++)
      #pragma unroll
      for (int j = 0; j < 4; j++) {
        sac[i][j] = MFMA16(aq[i][0], bk[j][0], sac[i][j]);
        sac[i][j] = MFMA16(aq[i][1], bk[j][1], sac[i][j]);
      }
  }

  // ---- maskless-max softmax (|S|<~5 bounded; masked -> exp==0 exactly) ----
  {
    float wmv[4];
    const int* wmp = word_mask + (b * 32 + s) * 64;
    #pragma unroll
    for (int j = 0; j < 4; j++)
      wmv[j] = (1.0f - (float)wmp[j * 16 + l16]) * -10000.0f;
    #pragma unroll
    for (int i = 0; i < 2; i++) {
      #pragma unroll
      for (int r = 0; r < 4; r++) {
        float vv[4];
        float sum = 0.f;
        #pragma unroll
        for (int j = 0; j < 4; j++) {
          vv[j] = __expf(sac[i][j][r] + wmv[j]);
          sum += vv[j];
        }
        sum += __shfl_xor(sum, 1);
        sum += __shfl_xor(sum, 2);
        sum += __shfl_xor(sum, 4);
        sum += __shfl_xor(sum, 8);
        const float inv = 1.0f / sum;
        const int row = w * 32 + i * 16 + quad * 4 + r;
        #pragma unroll
        for (int j = 0; j < 4; j++)
          Ps[row * 72 + j * 16 + l16] = f2bf(vv[j] * inv);
      }
    }
  }
  __syncthreads();

  // ---- O = P V ----
  f32x4 oac[2][4];
  #pragma unroll
  for (int i = 0; i < 2; i++)
    #pragma unroll
    for (int j = 0; j < 4; j++) oac[i][j] = zero4;
  {
    short8 ap[2][2], bv[4][2];
    #pragma unroll
    for (int i = 0; i < 2; i++)
      #pragma unroll
      for (int kb = 0; kb < 2; kb++)
        ap[i][kb] = *(short8*)&Ps[(w * 32 + i * 16 + l16) * 72 + kb * 32 + quad * 8];
    #pragma unroll
    for (int j = 0; j < 4; j++)
      #pragma unroll
      for (int kb = 0; kb < 2; kb++)
        bv[j][kb] = *(short8*)&Vs[(j * 16 + l16) * 72 + kb * 32 + quad * 8];
    #pragma unroll
    for (int i = 0; i < 2; i++)
      #pragma unroll
      for (int j = 0; j < 4; j++) {
        oac[i][j] = MFMA16(ap[i][0], bv[j][0], oac[i][j]);
        oac[i][j] = MFMA16(ap[i][1], bv[j][1], oac[i][j]);
      }
  }
  __syncthreads();  // K/V reads complete before O overlay write
  #pragma unroll
  for (int i = 0; i < 2; i++)
    #pragma unroll
    for (int j = 0; j < 4; j++)
      #pragma unroll
      for (int r = 0; r < 4; r++)
        Os[(w * 32 + i * 16 + quad * 4 + r) * 72 + j * 16 + l16] = f2bf(oac[i][j][r]);
  __syncthreads();

  // ---- wh store: 8 lanes/row x 16B -> 128B-contiguous segments ----
  {
    const int c8 = (tid & 7) * 8;
    #pragma unroll
    for (int i = 0; i < 4; i++) {
      const int row = i * 32 + (tid >> 3);
      short* dst = wh + (((size_t)(b * 128 + row)) * 32 + s) * 768 + h * 64;
      *(short8*)(dst + c8) = *(const short8*)&Os[row * 72 + c8];
    }
  }
}

// ---------------------------------------------------------------------------
// whc[h, bq, k] = sum_s probs2[bq,h,s] * wh[bq,s,k]   (bf16 out)
// ---------------------------------------------------------------------------
__global__ __launch_bounds__(256)
void whc_kernel(const short* __restrict__ wh, const float* __restrict__ probs2,
                short* __restrict__ whc) {
  __shared__ __align__(16) short whs[32 * 776];  // pad 768->776: conflict-free reads
  __shared__ float p2s[384];
  const int bq = blockIdx.x, tid = threadIdx.x;
  const short8* src = (const short8*)(wh + (size_t)bq * 24576);
  for (int t = tid; t < 3072; t += 256) {
    const int row = t / 96, c8 = (t % 96) * 8;
    *(short8*)&whs[row * 776 + c8] = src[t];
  }
  for (int p = tid; p < 384; p += 256) p2s[p] = probs2[(size_t)bq * 384 + p];
  __syncthreads();

  float acc[3][12];
  #pragma unroll
  for (int kk = 0; kk < 3; kk++)
    #pragma unroll
    for (int h = 0; h < 12; h++) acc[kk][h] = 0.f;

  for (int s = 0; s < 32; s++) {
    float p2r[12];
    #pragma unroll
    for (int h = 0; h < 12; h++) p2r[h] = p2s[h * 32 + s];
    #pragma unroll
    for (int kk = 0; kk < 3; kk++) {
      const float wv = bf2f(whs[s * 776 + kk * 256 + tid]);
      #pragma unroll
      for (int h = 0; h < 12; h++) acc[kk][h] += p2r[h] * wv;
    }
  }
  #pragma unroll
  for (int h = 0; h < 12; h++)
    #pragma unroll
    for (int kk = 0; kk < 3; kk++)
      whc[((size_t)h * 1024 + bq) * 768 + kk * 256 + tid] = f2bf(acc[kk][h]);
}

// ---------------------------------------------------------------------------
// outg: per-head GEMM  out[bq, h*64+d] = whc[h,bq,:] @ sv_w[:, h*64+d] + sv_b
// ---------------------------------------------------------------------------
__global__ __launch_bounds__(256)
void outg(const short* __restrict__ whc, const short* __restrict__ WTsv,
          const float* __restrict__ sv_b, float* __restrict__ out) {
  const int K = 768;
  __shared__ __align__(16) short As[128 * 32];
  __shared__ __align__(16) short Bs[64 * 32];
  const int tid = threadIdx.x;
  const int m0 = blockIdx.x * 128, h = blockIdx.y;
  const int w = tid >> 6, lane = tid & 63, quad = lane >> 4, l16 = lane & 15;
  const int wm = (w >> 1) * 64, wn = (w & 1) * 32;

  const int grow = w * 32 + (lane >> 2);
  const int kc = (lane & 3) * 8;
  const short* ag = whc + ((size_t)h * 1024 + m0 + grow) * K + kc;
  short* al = &As[(w * 32) * 32];
  const int growb = w * 16 + (lane >> 2);
  const short* bg = WTsv + (size_t)(h * 64 + growb) * K + kc;
  short* bl = &Bs[(w * 16) * 32];

  const f32x4 zero4 = {0.f, 0.f, 0.f, 0.f};
  f32x4 acc[4][2];
  #pragma unroll
  for (int i = 0; i < 4; i++)
    #pragma unroll
    for (int j = 0; j < 2; j++) acc[i][j] = zero4;

  for (int k0 = 0; k0 < K; k0 += 32) {
    __syncthreads();
    async_load16(ag, al);
    async_load16(ag + (size_t)16 * K, al + 16 * 32);
    async_load16(bg, bl);
    ag += 32;
    bg += 32;
    __syncthreads();
    short8 af[4], bf[2];
    #pragma unroll
    for (int i = 0; i < 4; i++)
      af[i] = *(short8*)&As[(wm + i * 16 + l16) * 32 + quad * 8];
    #pragma unroll
    for (int j = 0; j < 2; j++)
      bf[j] = *(short8*)&Bs[(wn + j * 16 + l16) * 32 + quad * 8];
    #pragma unroll
    for (int i = 0; i < 4; i++)
      #pragma unroll
      for (int j = 0; j < 2; j++)
        acc[i][j] = MFMA16(af[i], bf[j], acc[i][j]);
  }

  #pragma unroll
  for (int i = 0; i < 4; i++) {
    #pragma unroll
    for (int j = 0; j < 2; j++) {
      const int col = h * 64 + wn + j * 16 + l16;
      const float bv = sv_b[col];
      #pragma unroll
      for (int r = 0; r < 4; r++) {
        const int g = m0 + wm + i * 16 + quad * 4 + r;
        out[(size_t)g * 768 + col] = acc[i][j][r] + bv;
      }
    }
  }
}

// ---------------------------------------------------------------------------
extern "C" void kernel_launch(void* const* d_in, const int* in_sizes, int n_in,
                              void* d_out, int out_size, void* d_ws, size_t ws_size,
                              hipStream_t stream) {
  (void)in_sizes; (void)n_in; (void)out_size; (void)ws_size;
  const float* q_in      = (const float*)d_in[0];   // [8,128,768]
  const float* k_in      = (const float*)d_in[1];   // [8,32,64,768]
  const float* v_in      = (const float*)d_in[2];   // [8,32,64,768]
  const float* kvec      = (const float*)d_in[3];   // [8,32,768]
  const int*   word_mask = (const int*)d_in[4];     // [8,32,64]
  const int*   sent_mask = (const int*)d_in[5];     // [1024,32]
  const float* wq_w = (const float*)d_in[6],  *wq_b = (const float*)d_in[7];
  const float* wk_w = (const float*)d_in[8],  *wk_b = (const float*)d_in[9];
  const float* wv_w = (const float*)d_in[10], *wv_b = (const float*)d_in[11];
  const float* sq_w = (const float*)d_in[12], *sq_b = (const float*)d_in[13];
  const float* sk_w = (const float*)d_in[14], *sk_b = (const float*)d_in[15];
  const float* sv_w = (const float*)d_in[16], *sv_b = (const float*)d_in[17];
  float* out = (float*)d_out;

  const int WELEM = 768 * 768;

  static bool s_attr_done = false;
  if (!s_attr_done) {
    (void)hipFuncSetAttribute(reinterpret_cast<const void*>(&gemm_proj),
                              hipFuncAttributeMaxDynamicSharedMemorySize, 131072);
    s_attr_done = true;
  }

  char* ws = (char*)d_ws;
  size_t off = 0;
  auto alloc = [&](size_t bytes) -> void* {
    void* p = ws + off;
    off += (bytes + 255) & ~(size_t)255;
    return p;
  };
  short* WT  = (short*)alloc((size_t)6 * 768 * 768 * 2);   // wq,sq,wk,wv,sk,sv
  short* qbf = (short*)alloc((size_t)1024 * 768 * 2);
  short* kbf = (short*)alloc((size_t)16384 * 768 * 2);
  short* vbf = (short*)alloc((size_t)16384 * 768 * 2);
  short* kvb = (short*)alloc((size_t)256 * 768 * 2);
  short* qp  = (short*)alloc((size_t)1024 * 768 * 2);      // pre-scaled by 1/8
  short* kp  = (short*)alloc((size_t)16384 * 768 * 2);
  short* vT  = (short*)alloc((size_t)16384 * 768 * 2);     // [b,s,h,d,t]
  float* sqp = (float*)alloc((size_t)1024 * 768 * 4);
  float* skp = (float*)alloc((size_t)256 * 768 * 4);
  short* wh  = (short*)alloc((size_t)32768 * 768 * 2);     // 50.3 MB
  float* pr2 = (float*)alloc((size_t)1024 * 12 * 32 * 4);  //  1.6 MB
  short* whc = (short*)alloc((size_t)12 * 1024 * 768 * 2); // 18.9 MB [h,bq,k]

  // 1: weight transposes + grid-strided activation converts
  prep<<<dim3(5504), 256, 0, stream>>>(wq_w, sq_w, wk_w, wv_w, sk_w, sv_w, WT,
                                       q_in, k_in, v_in, kvec, qbf, kbf, vbf, kvb);
  // 2: ALL projections (z<2: kv 256^2 8-phase bodies; z==2: q+sq,sk small)
  gemm_proj<<<dim3(64, 3, 3), 512, 131072, stream>>>(
      kbf, vbf, qbf, kvb, WT, wk_b, wv_b, wq_b, sq_b, sk_b,
      kp, vT, qp, sqp, skp);
  // 3: word attention (+ sentence probs in blocks >= 3072)
  wattn_sp<<<dim3(4096), 256, 0, stream>>>(qp, kp, vT, word_mask, sqp, skp,
                                           sent_mask, wh, pr2);
  // 4: sentence contraction over s (commutes with sv projection)
  whc_kernel<<<dim3(1024), 256, 0, stream>>>(wh, pr2, whc);
  // 5: per-head output GEMM -> out
  outg<<<dim3(8, 12), 256, 0, stream>>>(whc, WT + 5 * WELEM, sv_b, out);
}

// Round 8
// 303.754 us; speedup vs baseline: 1.0953x; 1.0518x over previous
//
#include <hip/hip_runtime.h>
#include <hip/hip_bf16.h>

// Problem constants: BS=8, Q=128, S1=32, S2=64, H=768, NH=12, DH=64.

typedef __attribute__((ext_vector_type(8))) short short8;
typedef __attribute__((ext_vector_type(4))) short short4v;
typedef __attribute__((ext_vector_type(4))) float f32x4;

__device__ __forceinline__ short f2bf(float f) {
  __hip_bfloat16 b = __float2bfloat16(f);
  return __builtin_bit_cast(short, b);
}
__device__ __forceinline__ float bf2f(short s) {
  __hip_bfloat16 b = __builtin_bit_cast(__hip_bfloat16, s);
  return __bfloat162float(b);
}

#define MFMA16(a, b, c) __builtin_amdgcn_mfma_f32_16x16x32_bf16((a), (b), (c), 0, 0, 0)

// async 16B/lane global->LDS (wave-uniform LDS base; HW adds lane*16)
__device__ __forceinline__ void async_load16(const void* g, void* l) {
  auto l3 = (__attribute__((address_space(3))) void*)(uintptr_t)(
      reinterpret_cast<uintptr_t>(l));
  auto g1 = (const __attribute__((address_space(1))) void*)g;
  __builtin_amdgcn_global_load_lds(g1, l3, 16, 0, 0);
}

// raw barrier (no implicit vmcnt(0) drain) + compiler memory fence
#define KBAR()                                      \
  do {                                              \
    asm volatile("" ::: "memory");                  \
    __builtin_amdgcn_s_barrier();                   \
    asm volatile("" ::: "memory");                  \
  } while (0)
#define VMW(N) asm volatile("s_waitcnt vmcnt(" #N ")" ::: "memory")

// ---------------------------------------------------------------------------
// prep (R4-exact, measured-best): blocks [0,3456) = 6 weight transposes;
//       blocks [3456,16224) = one-shot fp32->bf16 convert of q/k/v/kvec.
// ---------------------------------------------------------------------------
__global__ __launch_bounds__(256)
void prep(const float* __restrict__ w0, const float* __restrict__ w1,
          const float* __restrict__ w2, const float* __restrict__ w3,
          const float* __restrict__ w4, const float* __restrict__ w5,
          short* __restrict__ WT,
          const float* __restrict__ q_in, const float* __restrict__ k_in,
          const float* __restrict__ v_in, const float* __restrict__ kvec,
          short* __restrict__ qbf, short* __restrict__ kbf,
          short* __restrict__ vbf, short* __restrict__ kvb) {
  const int id = blockIdx.x;
  const int tid = threadIdx.x;
  if (id < 3456) {
    __shared__ float tile[32][33];
    const int zz = id / 576, r = id % 576;
    const float* W = (zz == 0) ? w0 : (zz == 1) ? w1 : (zz == 2) ? w2
                   : (zz == 3) ? w3 : (zz == 4) ? w4 : w5;
    short* WTo = WT + (size_t)zz * 768 * 768;
    const int bx = (r % 24) * 32, by = (r / 24) * 32;
    const int tx = tid & 31, ty = tid >> 5;  // 32 x 8
    #pragma unroll
    for (int i = 0; i < 32; i += 8)
      tile[ty + i][tx] = W[(size_t)(by + ty + i) * 768 + bx + tx];
    __syncthreads();
    #pragma unroll
    for (int i = 0; i < 32; i += 8)
      WTo[(size_t)(bx + ty + i) * 768 + by + tx] = f2bf(tile[tx][ty + i]);
    return;
  }
  // ---- cvt: short8 units: q 98304 | k 1572864 | v 1572864 | kvec 24576 ----
  const int i = (id - 3456) * 256 + tid;
  const float* src;
  short* dst;
  int idx;
  if (i < 98304)        { src = q_in; dst = qbf; idx = i; }
  else if (i < 1671168) { src = k_in; dst = kbf; idx = i - 98304; }
  else if (i < 3244032) { src = v_in; dst = vbf; idx = i - 1671168; }
  else                  { src = kvec; dst = kvb; idx = i - 3244032; }
  const float4* s = (const float4*)src + (size_t)idx * 2;
  const float4 a = s[0], b = s[1];
  __align__(16) short tmp[8] = {f2bf(a.x), f2bf(a.y), f2bf(a.z), f2bf(a.w),
                                f2bf(b.x), f2bf(b.y), f2bf(b.z), f2bf(b.w)};
  *((short8*)dst + idx) = *(short8*)tmp;
}

// ---------------------------------------------------------------------------
// All projections, one launch, grid (64, 3, 3), 512 threads, 128 KiB dyn LDS:
//   z<2 : kv GEMM, 256x256 tile, BK=64, 8-phase schedule (R4-proven body).
//   z==2: EXACT gemm_small body (BK=32, 256 active threads). 108 blocks.
// ---------------------------------------------------------------------------
__global__ __launch_bounds__(512, 2)
void gemm_proj(const short* __restrict__ kbf, const short* __restrict__ vbf,
               const short* __restrict__ qbf, const short* __restrict__ kvb,
               const short* __restrict__ WT6,
               const float* __restrict__ wk_b, const float* __restrict__ wv_b,
               const float* __restrict__ wq_b, const float* __restrict__ sq_b,
               const float* __restrict__ sk_b,
               short* __restrict__ kp, short* __restrict__ vT,
               short* __restrict__ qp, float* __restrict__ sqp,
               float* __restrict__ skp) {
  const int K = 768, WELEM = 768 * 768;
  extern __shared__ __align__(16) char smem_c[];
  short* smem = (short*)smem_c;
  const int tid = threadIdx.x;
  const int w = tid >> 6, lane = tid & 63, quad = lane >> 4, l16 = lane & 15;
  const f32x4 zero4 = {0.f, 0.f, 0.f, 0.f};

  if (blockIdx.z < 2) {
    // ================= kv branch: 256^2 tile, 8-phase pipeline =============
    short* LA = smem;                  // [2 buf][256 rows][64 cols] bf16
    short* LB = smem + 2 * 256 * 64;   // [2 buf][256 rows][64 cols] bf16
    const int z = blockIdx.z;
    const short* Ag = z ? vbf : kbf;
    const short* Bg = z ? (WT6 + 3 * WELEM) : (WT6 + 2 * WELEM);
    const float* bias = z ? wv_b : wk_b;
    const int m0 = blockIdx.x * 256, n0 = blockIdx.y * 256;
    const int wr = w >> 2, wc = w & 3;  // 2 x 4 wave grid; wave tile 128x64

    // staging geometry: thread covers row (w*8 + lane/8), swizzled chunk
    // LDS[r][c] = G[r][c ^ (r&7)]  (chunk = 8 bf16 = 16B)
    const int srow = lane >> 3;              // 0..7
    const int schk = (lane & 7) ^ srow;      // pre-swizzled global chunk
    const short* ag0 = Ag + (size_t)(m0 + w * 8 + srow) * K + schk * 8;
    const short* bg0 = Bg + (size_t)(n0 + w * 8 + srow) * K + schk * 8;
    short* la0 = LA + (w * 8) * 64;          // wave-uniform LDS bases
    short* lb0 = LB + (w * 8) * 64;
    const int fsw = l16 & 7;                 // read-side swizzle (row&7)

    f32x4 acc[8][4];
    #pragma unroll
    for (int i = 0; i < 8; i++)
      #pragma unroll
      for (int j = 0; j < 4; j++) acc[i][j] = zero4;

    // stage one half-tile (128 rows x 64 cols) = 2 x global_load_lds / thread
    auto STG1 = [&](int op, int h, int kt) {
      if (kt >= 12) kt -= 2;  // tail: idempotent re-stage (same buf, same data)
      const int buf = kt & 1;
      const short* g = (op ? bg0 : ag0) + (size_t)h * 128 * K + (size_t)kt * 64;
      short* lb = (op ? lb0 : la0) + buf * 16384 + h * (128 * 64);
      async_load16(g, lb);
      async_load16(g + (size_t)64 * K, lb + 64 * 64);
    };

    short8 af[4][2];        // A frags of current IH: 4 i x 2 kb
    short8 bfr[2][2][2];    // B frags load-once: [JH][j][kb]

#define LDA_(BUF, IH)                                                        \
  _Pragma("unroll") for (int i = 0; i < 4; i++)                              \
    _Pragma("unroll") for (int kb = 0; kb < 2; kb++)                         \
      af[i][kb] = *(const short8*)&LA[(BUF)*16384 +                          \
          (wr * 128 + (IH)*64 + i * 16 + l16) * 64 +                         \
          (((kb * 4 + quad) ^ fsw) * 8)];
#define LDB_(BUF, JH)                                                        \
  _Pragma("unroll") for (int j = 0; j < 2; j++)                              \
    _Pragma("unroll") for (int kb = 0; kb < 2; kb++)                         \
      bfr[JH][j][kb] = *(const short8*)&LB[(BUF)*16384 +                     \
          (wc * 64 + (JH)*32 + j * 16 + l16) * 64 +                          \
          (((kb * 4 + quad) ^ fsw) * 8)];
#define MM_(IH, JH)                                                          \
  __builtin_amdgcn_s_setprio(1);                                             \
  _Pragma("unroll") for (int i = 0; i < 4; i++)                              \
    _Pragma("unroll") for (int j = 0; j < 2; j++) {                          \
      acc[(IH)*4 + i][(JH)*2 + j] =                                          \
          MFMA16(af[i][0], bfr[JH][j][0], acc[(IH)*4 + i][(JH)*2 + j]);      \
      acc[(IH)*4 + i][(JH)*2 + j] =                                          \
          MFMA16(af[i][1], bfr[JH][j][1], acc[(IH)*4 + i][(JH)*2 + j]);      \
    }                                                                        \
  __builtin_amdgcn_s_setprio(0);

    // ---- prologue: tile0 (8 loads) + B(1) (4 loads); drain tile0 ----
    STG1(0, 0, 0); STG1(0, 1, 0); STG1(1, 0, 0); STG1(1, 1, 0);
    STG1(1, 0, 1); STG1(1, 1, 1);
    VMW(4);   // tile 0 landed; B(1) in flight
    KBAR();

    // ---- main loop: 12 K-tiles = 6 iterations x 8 phases (R4 schedule) ----
    #pragma unroll 1
    for (int it = 0; it < 6; ++it) {
      const int o = 2 * it + 1, e2 = 2 * it + 2, o2 = 2 * it + 3;
      // P1
      LDA_(0, 0); LDB_(0, 0); STG1(0, 0, o); KBAR(); MM_(0, 0); KBAR();
      // P2
      LDB_(0, 1); STG1(0, 1, o); KBAR(); MM_(0, 1); KBAR();
      // P3
      LDA_(0, 1); STG1(1, 0, e2); KBAR(); MM_(1, 1); KBAR();
      // P4
      STG1(1, 1, e2); KBAR(); MM_(1, 0); VMW(4); KBAR();
      // P5
      LDA_(1, 0); LDB_(1, 0); STG1(0, 0, e2); KBAR(); MM_(0, 0); KBAR();
      // P6
      LDB_(1, 1); STG1(0, 1, e2); KBAR(); MM_(0, 1); KBAR();
      // P7
      LDA_(1, 1); STG1(1, 0, o2); KBAR(); MM_(1, 1); KBAR();
      // P8
      STG1(1, 1, o2); KBAR(); MM_(1, 0); VMW(4); KBAR();
    }
#undef LDA_
#undef LDB_
#undef MM_
    VMW(0);  // drain trailing idempotent stages before epilogue/endpgm

    // ---- epilogue ----
    if (z == 0) {
      #pragma unroll
      for (int I = 0; I < 8; I++)
        #pragma unroll
        for (int J = 0; J < 4; J++) {
          const int col = n0 + wc * 64 + J * 16 + l16;
          const float bv = bias[col];
          #pragma unroll
          for (int r = 0; r < 4; r++) {
            const int g = m0 + wr * 128 + I * 16 + quad * 4 + r;
            kp[(size_t)g * 768 + col] = f2bf(acc[I][J][r] + bv);
          }
        }
    } else {
      const int hh = (n0 >> 6) + wc;           // wave-constant head
      #pragma unroll
      for (int I = 0; I < 8; I++) {
        const int bs_ = (m0 >> 6) + wr * 2 + (I >> 2);  // global sentence
        const int t0 = (I & 3) * 16 + quad * 4;         // token base
        #pragma unroll
        for (int J = 0; J < 4; J++) {
          const int dd = J * 16 + l16;
          const float bv = bias[hh * 64 + dd];
          __align__(8) short tmp[4];
          #pragma unroll
          for (int r = 0; r < 4; r++) tmp[r] = f2bf(acc[I][J][r] + bv);
          *(short4v*)&vT[(((size_t)bs_ * 12 + hh) * 64 + dd) * 64 + t0] =
              *(short4v*)tmp;
        }
      }
    }
    return;
  }

  // ================= small branch (gemm_small body, BK=32) =================
  {
    const int id = blockIdx.x + 64 * blockIdx.y;  // 0..191
    if (id >= 108) return;
    short* As = smem;               // [128*32]
    short* Bs = smem + 128 * 32;    // [128*32]
    const int qmode = (id < 96);
    const int r = qmode ? id : (id - 96);
    const int bx = qmode ? (r % 8) : (r % 2);
    const int by = qmode ? (r / 8) : (r / 2);
    const short* A = qmode ? qbf : kvb;
    const short* WT = qmode ? (WT6 + 0 * WELEM) : (WT6 + 4 * WELEM);

    const int wm = (w >> 1) * 64, wn = (w & 1) * 64;  // valid for tid<256
    const int m0 = bx * 128, n0 = by * 128;
    const int grow = w * 32 + (lane >> 2);
    const int kc = (lane & 3) * 8;
    const short* ag = A + (size_t)(m0 + grow) * K + kc;
    const short* bg = WT + (size_t)(n0 + grow) * K + kc;
    short* al = &As[(w * 32) * 32];
    short* bl = &Bs[(w * 32) * 32];

    f32x4 acc[4][4];
    #pragma unroll
    for (int i = 0; i < 4; i++)
      #pragma unroll
      for (int j = 0; j < 4; j++) acc[i][j] = zero4;

    for (int k0 = 0; k0 < K; k0 += 32) {
      __syncthreads();
      if (tid < 256) {
        async_load16(ag, al);
        async_load16(ag + (size_t)16 * K, al + 16 * 32);
        async_load16(bg, bl);
        async_load16(bg + (size_t)16 * K, bl + 16 * 32);
      }
      ag += 32;
      bg += 32;
      __syncthreads();
      if (tid < 256) {
        short8 af[4], bf[4];
        #pragma unroll
        for (int i = 0; i < 4; i++)
          af[i] = *(short8*)&As[(wm + i * 16 + l16) * 32 + quad * 8];
        #pragma unroll
        for (int j = 0; j < 4; j++)
          bf[j] = *(short8*)&Bs[(wn + j * 16 + l16) * 32 + quad * 8];
        #pragma unroll
        for (int i = 0; i < 4; i++)
          #pragma unroll
          for (int j = 0; j < 4; j++)
            acc[i][j] = MFMA16(af[i], bf[j], acc[i][j]);
      }
    }
    if (tid >= 256) return;

    #pragma unroll
    for (int i = 0; i < 4; i++) {
      #pragma unroll
      for (int j = 0; j < 4; j++) {
        const int col = n0 + wn + j * 16 + l16;
        const float bv = qmode ? ((col < 768) ? wq_b[col] : sq_b[col - 768])
                               : sk_b[col];
        #pragma unroll
        for (int r4 = 0; r4 < 4; r4++) {
          const int g = m0 + wm + i * 16 + quad * 4 + r4;
          const float v = acc[i][j][r4] + bv;
          if (qmode) {
            if (col < 768) qp[(size_t)g * 768 + col] = f2bf(v * 0.125f);
            else sqp[(size_t)g * 768 + (col - 768)] = v;
          } else {
            skp[(size_t)g * 768 + col] = v;
          }
        }
      }
    }
  }
}

// ---------------------------------------------------------------------------
// blocks [0,3072): word-level attention per (b, s, h):
//   S = Qs Kt (Q pre-scaled by 1/8); maskless-max softmax; O = P V -> wh
//   Q-fragment + word-mask global loads hoisted above the staging barrier.
// blocks [3072,4096): sentence-attention probabilities per (b, q)
//   (softmax parallelized: 12 heads x 16 lanes, shfl_xor width-16 reduce)
// ---------------------------------------------------------------------------
__global__ __launch_bounds__(256)
void wattn_sp(const short* __restrict__ q_proj, const short* __restrict__ k_proj,
              const short* __restrict__ vT, const int* __restrict__ word_mask,
              const float* __restrict__ sq, const float* __restrict__ sk,
              const int* __restrict__ sent_mask, short* __restrict__ wh,
              float* __restrict__ probs2) {
  __shared__ __align__(16) short KVs[128 * 72];  // K rows 0-63, Vt rows 64-127; O overlay
  __shared__ __align__(16) short Ps[128 * 72];   // P bf16
  const int bid = blockIdx.x;
  const int tid = threadIdx.x;

  if (bid >= 3072) {
    // ---------------- sentence probs ----------------
    float* sc = (float*)KVs;  // 12*33 floats
    const int bq = bid - 3072;
    const int b = bq >> 7, q = bq & 127;
    for (int p = tid; p < 384; p += 256) {
      const int hh = p >> 5, ss = p & 31;
      const float4* a = (const float4*)(sq + ((size_t)(b * 128 + q)) * 768 + hh * 64);
      const float4* c = (const float4*)(sk + ((size_t)(b * 32 + ss)) * 768 + hh * 64);
      float d = 0.f;
      #pragma unroll
      for (int i = 0; i < 16; i++) {
        const float4 av = a[i], cv = c[i];
        d += av.x * cv.x + av.y * cv.y + av.z * cv.z + av.w * cv.w;
      }
      d = d * 0.125f + (1.0f - (float)sent_mask[bq * 32 + ss]) * -10000.0f;
      sc[hh * 33 + ss] = d;
    }
    __syncthreads();
    if (tid < 192) {
      // 12 heads x 16 lanes; each lane owns 2 of the 32 sentence scores.
      const int hh = tid >> 4, l = tid & 15;
      const float v0 = sc[hh * 33 + l], v1 = sc[hh * 33 + 16 + l];
      float mx = fmaxf(v0, v1);
      #pragma unroll
      for (int d = 1; d < 16; d <<= 1) mx = fmaxf(mx, __shfl_xor(mx, d, 16));
      const float e0 = __expf(v0 - mx), e1 = __expf(v1 - mx);
      float sum = e0 + e1;
      #pragma unroll
      for (int d = 1; d < 16; d <<= 1) sum += __shfl_xor(sum, d, 16);
      const float inv = 1.0f / sum;
      sc[hh * 33 + l] = e0 * inv;
      sc[hh * 33 + 16 + l] = e1 * inv;
    }
    __syncthreads();
    for (int p = tid; p < 384; p += 256) {
      const int hh = p >> 5, ss = p & 31;
      probs2[((size_t)bq * 12 + hh) * 32 + ss] = sc[hh * 33 + ss];
    }
    return;
  }

  // ---------------- word attention ----------------
  short* Ks = KVs;
  short* Vs = KVs + 64 * 72;
  short* Os = KVs;
  const int h = bid % 12, s = (bid / 12) % 32, b = bid / (12 * 32);
  const int w = tid >> 6, lane = tid & 63, quad = lane >> 4, l16 = lane & 15;
  const f32x4 zero4 = {0.f, 0.f, 0.f, 0.f};

  // ---- hoisted global loads (independent of LDS staging): Q frags + mask ----
  short8 aq[2][2];
  float wmv[4];
  {
    #pragma unroll
    for (int i = 0; i < 2; i++)
      #pragma unroll
      for (int kb = 0; kb < 2; kb++)
        aq[i][kb] = *(const short8*)(q_proj +
            ((size_t)(b * 128 + w * 32 + i * 16 + l16)) * 768 + h * 64 + kb * 32 + quad * 8);
    const int* wmp = word_mask + (b * 32 + s) * 64;
    #pragma unroll
    for (int j = 0; j < 4; j++)
      wmv[j] = (1.0f - (float)wmp[j * 16 + l16]) * -10000.0f;
  }

  // ---- stage K (tid<128) and Vt (tid>=128): 8 lanes/row x 16B ----
  {
    const int t2 = tid & 127;
    const int row8 = t2 >> 3;      // 0..15
    const int c8 = (t2 & 7) * 8;   // short offset within 64
    if (tid < 128) {
      const short* src = k_proj + ((size_t)((b * 32 + s) * 64)) * 768 + h * 64 + c8;
      #pragma unroll
      for (int i = 0; i < 4; i++) {
        const int r = row8 + i * 16;
        *(short8*)&Ks[r * 72 + c8] = *(const short8*)(src + (size_t)r * 768);
      }
    } else {
      const short* src = vT + ((size_t)((b * 32 + s) * 12 + h)) * 4096 + c8;
      #pragma unroll
      for (int i = 0; i < 4; i++) {
        const int r = row8 + i * 16;
        *(short8*)&Vs[r * 72 + c8] = *(const short8*)(src + (size_t)r * 64);
      }
    }
  }
  __syncthreads();

  // ---- S = Qs Kt ----
  f32x4 sac[2][4];
  #pragma unroll
  for (int i = 0; i < 2; i++)
    #pragma unroll
    for (int j = 0; j < 4; j++) sac[i][j] = zero4;
  {
    short8 bk[4][2];
    #pragma unroll
    for (int j = 0; j < 4; j++)
      #pragma unroll
      for (int kb = 0; kb < 2; kb++)
        bk[j][kb] = *(short8*)&Ks[(j * 16 + l16) * 72 + kb * 32 + quad * 8];
    #pragma unroll
    for (int i = 0; i < 2; i++)
      #pragma unroll
      for (int j = 0; j < 4; j++) {
        sac[i][j] = MFMA16(aq[i][0], bk[j][0], sac[i][j]);
        sac[i][j] = MFMA16(aq[i][1], bk[j][1], sac[i][j]);
      }
  }

  // ---- maskless-max softmax (|S|<~5 bounded; masked -> exp==0 exactly) ----
  {
    #pragma unroll
    for (int i = 0; i < 2; i++) {
      #pragma unroll
      for (int r = 0; r < 4; r++) {
        float vv[4];
        float sum = 0.f;
        #pragma unroll
        for (int j = 0; j < 4; j++) {
          vv[j] = __expf(sac[i][j][r] + wmv[j]);
          sum += vv[j];
        }
        sum += __shfl_xor(sum, 1);
        sum += __shfl_xor(sum, 2);
        sum += __shfl_xor(sum, 4);
        sum += __shfl_xor(sum, 8);
        const float inv = 1.0f / sum;
        const int row = w * 32 + i * 16 + quad * 4 + r;
        #pragma unroll
        for (int j = 0; j < 4; j++)
          Ps[row * 72 + j * 16 + l16] = f2bf(vv[j] * inv);
      }
    }
  }
  __syncthreads();

  // ---- O = P V ----
  f32x4 oac[2][4];
  #pragma unroll
  for (int i = 0; i < 2; i++)
    #pragma unroll
    for (int j = 0; j < 4; j++) oac[i][j] = zero4;
  {
    short8 ap[2][2], bv[4][2];
    #pragma unroll
    for (int i = 0; i < 2; i++)
      #pragma unroll
      for (int kb = 0; kb < 2; kb++)
        ap[i][kb] = *(short8*)&Ps[(w * 32 + i * 16 + l16) * 72 + kb * 32 + quad * 8];
    #pragma unroll
    for (int j = 0; j < 4; j++)
      #pragma unroll
      for (int kb = 0; kb < 2; kb++)
        bv[j][kb] = *(short8*)&Vs[(j * 16 + l16) * 72 + kb * 32 + quad * 8];
    #pragma unroll
    for (int i = 0; i < 2; i++)
      #pragma unroll
      for (int j = 0; j < 4; j++) {
        oac[i][j] = MFMA16(ap[i][0], bv[j][0], oac[i][j]);
        oac[i][j] = MFMA16(ap[i][1], bv[j][1], oac[i][j]);
      }
  }
  __syncthreads();  // K/V reads complete before O overlay write
  #pragma unroll
  for (int i = 0; i < 2; i++)
    #pragma unroll
    for (int j = 0; j < 4; j++)
      #pragma unroll
      for (int r = 0; r < 4; r++)
        Os[(w * 32 + i * 16 + quad * 4 + r) * 72 + j * 16 + l16] = f2bf(oac[i][j][r]);
  __syncthreads();

  // ---- wh store: 8 lanes/row x 16B -> 128B-contiguous segments ----
  {
    const int c8 = (tid & 7) * 8;
    #pragma unroll
    for (int i = 0; i < 4; i++) {
      const int row = i * 32 + (tid >> 3);
      short* dst = wh + (((size_t)(b * 128 + row)) * 32 + s) * 768 + h * 64;
      *(short8*)(dst + c8) = *(const short8*)&Os[row * 72 + c8];
    }
  }
}

// ---------------------------------------------------------------------------
// whc[h, bq, k] = sum_s probs2[bq,h,s] * wh[bq,s,k]   (bf16 out)
// ---------------------------------------------------------------------------
__global__ __launch_bounds__(256)
void whc_kernel(const short* __restrict__ wh, const float* __restrict__ probs2,
                short* __restrict__ whc) {
  __shared__ __align__(16) short whs[32 * 776];  // pad 768->776: conflict-free reads
  __shared__ float p2s[384];
  const int bq = blockIdx.x, tid = threadIdx.x;
  const short8* src = (const short8*)(wh + (size_t)bq * 24576);
  for (int t = tid; t < 3072; t += 256) {
    const int row = t / 96, c8 = (t % 96) * 8;
    *(short8*)&whs[row * 776 + c8] = src[t];
  }
  for (int p = tid; p < 384; p += 256) p2s[p] = probs2[(size_t)bq * 384 + p];
  __syncthreads();

  float acc[3][12];
  #pragma unroll
  for (int kk = 0; kk < 3; kk++)
    #pragma unroll
    for (int h = 0; h < 12; h++) acc[kk][h] = 0.f;

  for (int s = 0; s < 32; s++) {
    float p2r[12];
    #pragma unroll
    for (int h = 0; h < 12; h++) p2r[h] = p2s[h * 32 + s];
    #pragma unroll
    for (int kk = 0; kk < 3; kk++) {
      const float wv = bf2f(whs[s * 776 + kk * 256 + tid]);
      #pragma unroll
      for (int h = 0; h < 12; h++) acc[kk][h] += p2r[h] * wv;
    }
  }
  #pragma unroll
  for (int h = 0; h < 12; h++)
    #pragma unroll
    for (int kk = 0; kk < 3; kk++)
      whc[((size_t)h * 1024 + bq) * 768 + kk * 256 + tid] = f2bf(acc[kk][h]);
}

// ---------------------------------------------------------------------------
// outg: per-head GEMM  out[bq, h*64+d] = whc[h,bq,:] @ sv_w[:, h*64+d] + sv_b
// grid (16, 12): 64x64 tile, BK=32, 192 blocks (was 96 — better CU coverage).
// Waves 2x2: wm=(w>>1)*32, wn=(w&1)*32; acc[2][2].
// ---------------------------------------------------------------------------
__global__ __launch_bounds__(256)
void outg(const short* __restrict__ whc, const short* __restrict__ WTsv,
          const float* __restrict__ sv_b, float* __restrict__ out) {
  const int K = 768;
  __shared__ __align__(16) short As[64 * 32];
  __shared__ __align__(16) short Bs[64 * 32];
  const int tid = threadIdx.x;
  const int m0 = blockIdx.x * 64, h = blockIdx.y;
  const int w = tid >> 6, lane = tid & 63, quad = lane >> 4, l16 = lane & 15;
  const int wm = (w >> 1) * 32, wn = (w & 1) * 32;

  // staging: wave w covers 16 rows (w*16 + lane/4), 4 lanes x 16B per row
  const int grow = w * 16 + (lane >> 2);
  const int kc = (lane & 3) * 8;
  const short* ag = whc + ((size_t)h * 1024 + m0 + grow) * K + kc;
  short* al = &As[(w * 16) * 32];
  const short* bg = WTsv + (size_t)(h * 64 + grow) * K + kc;
  short* bl = &Bs[(w * 16) * 32];

  const f32x4 zero4 = {0.f, 0.f, 0.f, 0.f};
  f32x4 acc[2][2];
  #pragma unroll
  for (int i = 0; i < 2; i++)
    #pragma unroll
    for (int j = 0; j < 2; j++) acc[i][j] = zero4;

  for (int k0 = 0; k0 < K; k0 += 32) {
    __syncthreads();
    async_load16(ag, al);
    async_load16(bg, bl);
    ag += 32;
    bg += 32;
    __syncthreads();
    short8 af[2], bf[2];
    #pragma unroll
    for (int i = 0; i < 2; i++)
      af[i] = *(short8*)&As[(wm + i * 16 + l16) * 32 + quad * 8];
    #pragma unroll
    for (int j = 0; j < 2; j++)
      bf[j] = *(short8*)&Bs[(wn + j * 16 + l16) * 32 + quad * 8];
    #pragma unroll
    for (int i = 0; i < 2; i++)
      #pragma unroll
      for (int j = 0; j < 2; j++)
        acc[i][j] = MFMA16(af[i], bf[j], acc[i][j]);
  }

  #pragma unroll
  for (int i = 0; i < 2; i++) {
    #pragma unroll
    for (int j = 0; j < 2; j++) {
      const int col = h * 64 + wn + j * 16 + l16;
      const float bv = sv_b[col];
      #pragma unroll
      for (int r = 0; r < 2 * 2; r++) {
        const int g = m0 + wm + i * 16 + quad * 4 + r;
        if (r < 4) out[(size_t)g * 768 + col] = acc[i][j][r] + bv;
      }
    }
  }
}

// ---------------------------------------------------------------------------
extern "C" void kernel_launch(void* const* d_in, const int* in_sizes, int n_in,
                              void* d_out, int out_size, void* d_ws, size_t ws_size,
                              hipStream_t stream) {
  (void)in_sizes; (void)n_in; (void)out_size; (void)ws_size;
  const float* q_in      = (const float*)d_in[0];   // [8,128,768]
  const float* k_in      = (const float*)d_in[1];   // [8,32,64,768]
  const float* v_in      = (const float*)d_in[2];   // [8,32,64,768]
  const float* kvec      = (const float*)d_in[3];   // [8,32,768]
  const int*   word_mask = (const int*)d_in[4];     // [8,32,64]
  const int*   sent_mask = (const int*)d_in[5];     // [1024,32]
  const float* wq_w = (const float*)d_in[6],  *wq_b = (const float*)d_in[7];
  const float* wk_w = (const float*)d_in[8],  *wk_b = (const float*)d_in[9];
  const float* wv_w = (const float*)d_in[10], *wv_b = (const float*)d_in[11];
  const float* sq_w = (const float*)d_in[12], *sq_b = (const float*)d_in[13];
  const float* sk_w = (const float*)d_in[14], *sk_b = (const float*)d_in[15];
  const float* sv_w = (const float*)d_in[16], *sv_b = (const float*)d_in[17];
  float* out = (float*)d_out;

  const int WELEM = 768 * 768;

  static bool s_attr_done = false;
  if (!s_attr_done) {
    (void)hipFuncSetAttribute(reinterpret_cast<const void*>(&gemm_proj),
                              hipFuncAttributeMaxDynamicSharedMemorySize, 131072);
    s_attr_done = true;
  }

  char* ws = (char*)d_ws;
  size_t off = 0;
  auto alloc = [&](size_t bytes) -> void* {
    void* p = ws + off;
    off += (bytes + 255) & ~(size_t)255;
    return p;
  };
  short* WT  = (short*)alloc((size_t)6 * 768 * 768 * 2);   // wq,sq,wk,wv,sk,sv
  short* qbf = (short*)alloc((size_t)1024 * 768 * 2);
  short* kbf = (short*)alloc((size_t)16384 * 768 * 2);
  short* vbf = (short*)alloc((size_t)16384 * 768 * 2);
  short* kvb = (short*)alloc((size_t)256 * 768 * 2);
  short* qp  = (short*)alloc((size_t)1024 * 768 * 2);      // pre-scaled by 1/8
  short* kp  = (short*)alloc((size_t)16384 * 768 * 2);
  short* vT  = (short*)alloc((size_t)16384 * 768 * 2);     // [b,s,h,d,t]
  float* sqp = (float*)alloc((size_t)1024 * 768 * 4);
  float* skp = (float*)alloc((size_t)256 * 768 * 4);
  short* wh  = (short*)alloc((size_t)32768 * 768 * 2);     // 50.3 MB
  float* pr2 = (float*)alloc((size_t)1024 * 12 * 32 * 4);  //  1.6 MB
  short* whc = (short*)alloc((size_t)12 * 1024 * 768 * 2); // 18.9 MB [h,bq,k]

  // 1: weight transposes + activation converts (R4-exact config)
  prep<<<dim3(16224), 256, 0, stream>>>(wq_w, sq_w, wk_w, wv_w, sk_w, sv_w, WT,
                                        q_in, k_in, v_in, kvec, qbf, kbf, vbf, kvb);
  // 2: ALL projections (z<2: kv 256^2 8-phase bodies; z==2: q+sq,sk small)
  gemm_proj<<<dim3(64, 3, 3), 512, 131072, stream>>>(
      kbf, vbf, qbf, kvb, WT, wk_b, wv_b, wq_b, sq_b, sk_b,
      kp, vT, qp, sqp, skp);
  // 3: word attention (+ sentence probs in blocks >= 3072)
  wattn_sp<<<dim3(4096), 256, 0, stream>>>(qp, kp, vT, word_mask, sqp, skp,
                                           sent_mask, wh, pr2);
  // 4: sentence contraction over s (commutes with sv projection)
  whc_kernel<<<dim3(1024), 256, 0, stream>>>(wh, pr2, whc);
  // 5: per-head output GEMM -> out (192 blocks, 64x64 tiles)
  outg<<<dim3(16, 12), 256, 0, stream>>>(whc, WT + 5 * WELEM, sv_b, out);
}

// Round 9
// 298.261 us; speedup vs baseline: 1.1155x; 1.0184x over previous
//
#include <hip/hip_runtime.h>
#include <hip/hip_bf16.h>

// Problem constants: BS=8, Q=128, S1=32, S2=64, H=768, NH=12, DH=64.

typedef __attribute__((ext_vector_type(8))) short short8;
typedef __attribute__((ext_vector_type(4))) short short4v;
typedef __attribute__((ext_vector_type(4))) float f32x4;

__device__ __forceinline__ short f2bf(float f) {
  __hip_bfloat16 b = __float2bfloat16(f);
  return __builtin_bit_cast(short, b);
}
__device__ __forceinline__ float bf2f(short s) {
  __hip_bfloat16 b = __builtin_bit_cast(__hip_bfloat16, s);
  return __bfloat162float(b);
}

#define MFMA16(a, b, c) __builtin_amdgcn_mfma_f32_16x16x32_bf16((a), (b), (c), 0, 0, 0)

// async 16B/lane global->LDS (wave-uniform LDS base; HW adds lane*16)
__device__ __forceinline__ void async_load16(const void* g, void* l) {
  auto l3 = (__attribute__((address_space(3))) void*)(uintptr_t)(
      reinterpret_cast<uintptr_t>(l));
  auto g1 = (const __attribute__((address_space(1))) void*)g;
  __builtin_amdgcn_global_load_lds(g1, l3, 16, 0, 0);
}

// raw barrier (no implicit vmcnt(0) drain) + compiler memory fence
#define KBAR()                                      \
  do {                                              \
    asm volatile("" ::: "memory");                  \
    __builtin_amdgcn_s_barrier();                   \
    asm volatile("" ::: "memory");                  \
  } while (0)
#define VMW(N) asm volatile("s_waitcnt vmcnt(" #N ")" ::: "memory")

// ---------------------------------------------------------------------------
// prep: blocks [0,3456) = 6 weight transposes (fp32 -> bf16, WT[n][k]),
//       transposed store vectorized to short4 (8B/lane, 1 store/thread);
//       blocks [3456,16224) = one-shot fp32->bf16 convert of q/k/v/kvec.
// ---------------------------------------------------------------------------
__global__ __launch_bounds__(256)
void prep(const float* __restrict__ w0, const float* __restrict__ w1,
          const float* __restrict__ w2, const float* __restrict__ w3,
          const float* __restrict__ w4, const float* __restrict__ w5,
          short* __restrict__ WT,
          const float* __restrict__ q_in, const float* __restrict__ k_in,
          const float* __restrict__ v_in, const float* __restrict__ kvec,
          short* __restrict__ qbf, short* __restrict__ kbf,
          short* __restrict__ vbf, short* __restrict__ kvb) {
  const int id = blockIdx.x;
  const int tid = threadIdx.x;
  if (id < 3456) {
    __shared__ float tile[32][33];
    const int zz = id / 576, r = id % 576;
    const float* W = (zz == 0) ? w0 : (zz == 1) ? w1 : (zz == 2) ? w2
                   : (zz == 3) ? w3 : (zz == 4) ? w4 : w5;
    short* WTo = WT + (size_t)zz * 768 * 768;
    const int bx = (r % 24) * 32, by = (r / 24) * 32;
    const int tx = tid & 31, ty = tid >> 5;  // 32 x 8
    #pragma unroll
    for (int i = 0; i < 32; i += 8)
      tile[ty + i][tx] = W[(size_t)(by + ty + i) * 768 + bx + tx];
    __syncthreads();
    // transposed store: WTo[bx+n][by+m] = tile[m][n]; thread -> (n=tid>>3,
    // m = (tid&7)*4 .. +3) => one aligned short4 store per thread.
    const int r2 = tid >> 3;        // output row within tile (0..31)
    const int cg = (tid & 7) * 4;   // output col group (0,4,..,28)
    __align__(8) short t4[4];
    #pragma unroll
    for (int k2 = 0; k2 < 4; k2++) t4[k2] = f2bf(tile[cg + k2][r2]);
    *(short4v*)&WTo[(size_t)(bx + r2) * 768 + by + cg] = *(short4v*)t4;
    return;
  }
  // ---- cvt: short8 units: q 98304 | k 1572864 | v 1572864 | kvec 24576 ----
  const int i = (id - 3456) * 256 + tid;
  const float* src;
  short* dst;
  int idx;
  if (i < 98304)        { src = q_in; dst = qbf; idx = i; }
  else if (i < 1671168) { src = k_in; dst = kbf; idx = i - 98304; }
  else if (i < 3244032) { src = v_in; dst = vbf; idx = i - 1671168; }
  else                  { src = kvec; dst = kvb; idx = i - 3244032; }
  const float4* s = (const float4*)src + (size_t)idx * 2;
  const float4 a = s[0], b = s[1];
  __align__(16) short tmp[8] = {f2bf(a.x), f2bf(a.y), f2bf(a.z), f2bf(a.w),
                                f2bf(b.x), f2bf(b.y), f2bf(b.z), f2bf(b.w)};
  *((short8*)dst + idx) = *(short8*)tmp;
}

// ---------------------------------------------------------------------------
// All projections, one launch, grid (64, 3, 3), 512 threads, 128 KiB dyn LDS:
//   z<2 : kv GEMM, 256x256 tile, BK=64, 8-phase schedule (R4-proven body).
//   z==2: EXACT gemm_small body (BK=32, 256 active threads). 108 blocks.
// ---------------------------------------------------------------------------
__global__ __launch_bounds__(512, 2)
void gemm_proj(const short* __restrict__ kbf, const short* __restrict__ vbf,
               const short* __restrict__ qbf, const short* __restrict__ kvb,
               const short* __restrict__ WT6,
               const float* __restrict__ wk_b, const float* __restrict__ wv_b,
               const float* __restrict__ wq_b, const float* __restrict__ sq_b,
               const float* __restrict__ sk_b,
               short* __restrict__ kp, short* __restrict__ vT,
               short* __restrict__ qp, float* __restrict__ sqp,
               float* __restrict__ skp) {
  const int K = 768, WELEM = 768 * 768;
  extern __shared__ __align__(16) char smem_c[];
  short* smem = (short*)smem_c;
  const int tid = threadIdx.x;
  const int w = tid >> 6, lane = tid & 63, quad = lane >> 4, l16 = lane & 15;
  const f32x4 zero4 = {0.f, 0.f, 0.f, 0.f};

  if (blockIdx.z < 2) {
    // ================= kv branch: 256^2 tile, 8-phase pipeline =============
    short* LA = smem;                  // [2 buf][256 rows][64 cols] bf16
    short* LB = smem + 2 * 256 * 64;   // [2 buf][256 rows][64 cols] bf16
    const int z = blockIdx.z;
    const short* Ag = z ? vbf : kbf;
    const short* Bg = z ? (WT6 + 3 * WELEM) : (WT6 + 2 * WELEM);
    const float* bias = z ? wv_b : wk_b;
    const int m0 = blockIdx.x * 256, n0 = blockIdx.y * 256;
    const int wr = w >> 2, wc = w & 3;  // 2 x 4 wave grid; wave tile 128x64

    // staging geometry: thread covers row (w*8 + lane/8), swizzled chunk
    // LDS[r][c] = G[r][c ^ (r&7)]  (chunk = 8 bf16 = 16B)
    const int srow = lane >> 3;              // 0..7
    const int schk = (lane & 7) ^ srow;      // pre-swizzled global chunk
    const short* ag0 = Ag + (size_t)(m0 + w * 8 + srow) * K + schk * 8;
    const short* bg0 = Bg + (size_t)(n0 + w * 8 + srow) * K + schk * 8;
    short* la0 = LA + (w * 8) * 64;          // wave-uniform LDS bases
    short* lb0 = LB + (w * 8) * 64;
    const int fsw = l16 & 7;                 // read-side swizzle (row&7)

    f32x4 acc[8][4];
    #pragma unroll
    for (int i = 0; i < 8; i++)
      #pragma unroll
      for (int j = 0; j < 4; j++) acc[i][j] = zero4;

    // stage one half-tile (128 rows x 64 cols) = 2 x global_load_lds / thread
    auto STG1 = [&](int op, int h, int kt) {
      if (kt >= 12) kt -= 2;  // tail: idempotent re-stage (same buf, same data)
      const int buf = kt & 1;
      const short* g = (op ? bg0 : ag0) + (size_t)h * 128 * K + (size_t)kt * 64;
      short* lb = (op ? lb0 : la0) + buf * 16384 + h * (128 * 64);
      async_load16(g, lb);
      async_load16(g + (size_t)64 * K, lb + 64 * 64);
    };

    short8 af[4][2];        // A frags of current IH: 4 i x 2 kb
    short8 bfr[2][2][2];    // B frags load-once: [JH][j][kb]

#define LDA_(BUF, IH)                                                        \
  _Pragma("unroll") for (int i = 0; i < 4; i++)                              \
    _Pragma("unroll") for (int kb = 0; kb < 2; kb++)                         \
      af[i][kb] = *(const short8*)&LA[(BUF)*16384 +                          \
          (wr * 128 + (IH)*64 + i * 16 + l16) * 64 +                         \
          (((kb * 4 + quad) ^ fsw) * 8)];
#define LDB_(BUF, JH)                                                        \
  _Pragma("unroll") for (int j = 0; j < 2; j++)                              \
    _Pragma("unroll") for (int kb = 0; kb < 2; kb++)                         \
      bfr[JH][j][kb] = *(const short8*)&LB[(BUF)*16384 +                     \
          (wc * 64 + (JH)*32 + j * 16 + l16) * 64 +                          \
          (((kb * 4 + quad) ^ fsw) * 8)];
#define MM_(IH, JH)                                                          \
  __builtin_amdgcn_s_setprio(1);                                             \
  _Pragma("unroll") for (int i = 0; i < 4; i++)                              \
    _Pragma("unroll") for (int j = 0; j < 2; j++) {                          \
      acc[(IH)*4 + i][(JH)*2 + j] =                                          \
          MFMA16(af[i][0], bfr[JH][j][0], acc[(IH)*4 + i][(JH)*2 + j]);      \
      acc[(IH)*4 + i][(JH)*2 + j] =                                          \
          MFMA16(af[i][1], bfr[JH][j][1], acc[(IH)*4 + i][(JH)*2 + j]);      \
    }                                                                        \
  __builtin_amdgcn_s_setprio(0);

    // ---- prologue: tile0 (8 loads) + B(1) (4 loads); drain tile0 ----
    STG1(0, 0, 0); STG1(0, 1, 0); STG1(1, 0, 0); STG1(1, 1, 0);
    STG1(1, 0, 1); STG1(1, 1, 1);
    VMW(4);   // tile 0 landed; B(1) in flight
    KBAR();

    // ---- main loop: 12 K-tiles = 6 iterations x 8 phases (R4 schedule) ----
    #pragma unroll 1
    for (int it = 0; it < 6; ++it) {
      const int o = 2 * it + 1, e2 = 2 * it + 2, o2 = 2 * it + 3;
      // P1
      LDA_(0, 0); LDB_(0, 0); STG1(0, 0, o); KBAR(); MM_(0, 0); KBAR();
      // P2
      LDB_(0, 1); STG1(0, 1, o); KBAR(); MM_(0, 1); KBAR();
      // P3
      LDA_(0, 1); STG1(1, 0, e2); KBAR(); MM_(1, 1); KBAR();
      // P4
      STG1(1, 1, e2); KBAR(); MM_(1, 0); VMW(4); KBAR();
      // P5
      LDA_(1, 0); LDB_(1, 0); STG1(0, 0, e2); KBAR(); MM_(0, 0); KBAR();
      // P6
      LDB_(1, 1); STG1(0, 1, e2); KBAR(); MM_(0, 1); KBAR();
      // P7
      LDA_(1, 1); STG1(1, 0, o2); KBAR(); MM_(1, 1); KBAR();
      // P8
      STG1(1, 1, o2); KBAR(); MM_(1, 0); VMW(4); KBAR();
    }
#undef LDA_
#undef LDB_
#undef MM_
    VMW(0);  // drain trailing idempotent stages before epilogue/endpgm

    // ---- epilogue ----
    if (z == 0) {
      #pragma unroll
      for (int I = 0; I < 8; I++)
        #pragma unroll
        for (int J = 0; J < 4; J++) {
          const int col = n0 + wc * 64 + J * 16 + l16;
          const float bv = bias[col];
          #pragma unroll
          for (int r = 0; r < 4; r++) {
            const int g = m0 + wr * 128 + I * 16 + quad * 4 + r;
            kp[(size_t)g * 768 + col] = f2bf(acc[I][J][r] + bv);
          }
        }
    } else {
      const int hh = (n0 >> 6) + wc;           // wave-constant head
      #pragma unroll
      for (int I = 0; I < 8; I++) {
        const int bs_ = (m0 >> 6) + wr * 2 + (I >> 2);  // global sentence
        const int t0 = (I & 3) * 16 + quad * 4;         // token base
        #pragma unroll
        for (int J = 0; J < 4; J++) {
          const int dd = J * 16 + l16;
          const float bv = bias[hh * 64 + dd];
          __align__(8) short tmp[4];
          #pragma unroll
          for (int r = 0; r < 4; r++) tmp[r] = f2bf(acc[I][J][r] + bv);
          *(short4v*)&vT[(((size_t)bs_ * 12 + hh) * 64 + dd) * 64 + t0] =
              *(short4v*)tmp;
        }
      }
    }
    return;
  }

  // ================= small branch (gemm_small body, BK=32) =================
  {
    const int id = blockIdx.x + 64 * blockIdx.y;  // 0..191
    if (id >= 108) return;
    short* As = smem;               // [128*32]
    short* Bs = smem + 128 * 32;    // [128*32]
    const int qmode = (id < 96);
    const int r = qmode ? id : (id - 96);
    const int bx = qmode ? (r % 8) : (r % 2);
    const int by = qmode ? (r / 8) : (r / 2);
    const short* A = qmode ? qbf : kvb;
    const short* WT = qmode ? (WT6 + 0 * WELEM) : (WT6 + 4 * WELEM);

    const int wm = (w >> 1) * 64, wn = (w & 1) * 64;  // valid for tid<256
    const int m0 = bx * 128, n0 = by * 128;
    const int grow = w * 32 + (lane >> 2);
    const int kc = (lane & 3) * 8;
    const short* ag = A + (size_t)(m0 + grow) * K + kc;
    const short* bg = WT + (size_t)(n0 + grow) * K + kc;
    short* al = &As[(w * 32) * 32];
    short* bl = &Bs[(w * 32) * 32];

    f32x4 acc[4][4];
    #pragma unroll
    for (int i = 0; i < 4; i++)
      #pragma unroll
      for (int j = 0; j < 4; j++) acc[i][j] = zero4;

    for (int k0 = 0; k0 < K; k0 += 32) {
      __syncthreads();
      if (tid < 256) {
        async_load16(ag, al);
        async_load16(ag + (size_t)16 * K, al + 16 * 32);
        async_load16(bg, bl);
        async_load16(bg + (size_t)16 * K, bl + 16 * 32);
      }
      ag += 32;
      bg += 32;
      __syncthreads();
      if (tid < 256) {
        short8 af[4], bf[4];
        #pragma unroll
        for (int i = 0; i < 4; i++)
          af[i] = *(short8*)&As[(wm + i * 16 + l16) * 32 + quad * 8];
        #pragma unroll
        for (int j = 0; j < 4; j++)
          bf[j] = *(short8*)&Bs[(wn + j * 16 + l16) * 32 + quad * 8];
        #pragma unroll
        for (int i = 0; i < 4; i++)
          #pragma unroll
          for (int j = 0; j < 4; j++)
            acc[i][j] = MFMA16(af[i], bf[j], acc[i][j]);
      }
    }
    if (tid >= 256) return;

    #pragma unroll
    for (int i = 0; i < 4; i++) {
      #pragma unroll
      for (int j = 0; j < 4; j++) {
        const int col = n0 + wn + j * 16 + l16;
        const float bv = qmode ? ((col < 768) ? wq_b[col] : sq_b[col - 768])
                               : sk_b[col];
        #pragma unroll
        for (int r4 = 0; r4 < 4; r4++) {
          const int g = m0 + wm + i * 16 + quad * 4 + r4;
          const float v = acc[i][j][r4] + bv;
          if (qmode) {
            if (col < 768) qp[(size_t)g * 768 + col] = f2bf(v * 0.125f);
            else sqp[(size_t)g * 768 + (col - 768)] = v;
          } else {
            skp[(size_t)g * 768 + col] = v;
          }
        }
      }
    }
  }
}

// ---------------------------------------------------------------------------
// 3072 blocks: word-level attention per (b, s, h):
//   S = Qs Kt (Q pre-scaled by 1/8); maskless-max softmax; O = P V -> wh
//   Q-fragment + word-mask global loads hoisted above the staging barrier.
// (sentence-probs moved into whc_kernel)
// ---------------------------------------------------------------------------
__global__ __launch_bounds__(256)
void wattn_sp(const short* __restrict__ q_proj, const short* __restrict__ k_proj,
              const short* __restrict__ vT, const int* __restrict__ word_mask,
              short* __restrict__ wh) {
  __shared__ __align__(16) short KVs[128 * 72];  // K rows 0-63, Vt rows 64-127; O overlay
  __shared__ __align__(16) short Ps[128 * 72];   // P bf16
  const int bid = blockIdx.x;
  const int tid = threadIdx.x;

  short* Ks = KVs;
  short* Vs = KVs + 64 * 72;
  short* Os = KVs;
  const int h = bid % 12, s = (bid / 12) % 32, b = bid / (12 * 32);
  const int w = tid >> 6, lane = tid & 63, quad = lane >> 4, l16 = lane & 15;
  const f32x4 zero4 = {0.f, 0.f, 0.f, 0.f};

  // ---- hoisted global loads (independent of LDS staging): Q frags + mask ----
  short8 aq[2][2];
  float wmv[4];
  {
    #pragma unroll
    for (int i = 0; i < 2; i++)
      #pragma unroll
      for (int kb = 0; kb < 2; kb++)
        aq[i][kb] = *(const short8*)(q_proj +
            ((size_t)(b * 128 + w * 32 + i * 16 + l16)) * 768 + h * 64 + kb * 32 + quad * 8);
    const int* wmp = word_mask + (b * 32 + s) * 64;
    #pragma unroll
    for (int j = 0; j < 4; j++)
      wmv[j] = (1.0f - (float)wmp[j * 16 + l16]) * -10000.0f;
  }

  // ---- stage K (tid<128) and Vt (tid>=128): 8 lanes/row x 16B ----
  {
    const int t2 = tid & 127;
    const int row8 = t2 >> 3;      // 0..15
    const int c8 = (t2 & 7) * 8;   // short offset within 64
    if (tid < 128) {
      const short* src = k_proj + ((size_t)((b * 32 + s) * 64)) * 768 + h * 64 + c8;
      #pragma unroll
      for (int i = 0; i < 4; i++) {
        const int r = row8 + i * 16;
        *(short8*)&Ks[r * 72 + c8] = *(const short8*)(src + (size_t)r * 768);
      }
    } else {
      const short* src = vT + ((size_t)((b * 32 + s) * 12 + h)) * 4096 + c8;
      #pragma unroll
      for (int i = 0; i < 4; i++) {
        const int r = row8 + i * 16;
        *(short8*)&Vs[r * 72 + c8] = *(const short8*)(src + (size_t)r * 64);
      }
    }
  }
  __syncthreads();

  // ---- S = Qs Kt ----
  f32x4 sac[2][4];
  #pragma unroll
  for (int i = 0; i < 2; i++)
    #pragma unroll
    for (int j = 0; j < 4; j++) sac[i][j] = zero4;
  {
    short8 bk[4][2];
    #pragma unroll
    for (int j = 0; j < 4; j++)
      #pragma unroll
      for (int kb = 0; kb < 2; kb++)
        bk[j][kb] = *(short8*)&Ks[(j * 16 + l16) * 72 + kb * 32 + quad * 8];
    #pragma unroll
    for (int i = 0; i < 2; i++)
      #pragma unroll
      for (int j = 0; j < 4; j++) {
        sac[i][j] = MFMA16(aq[i][0], bk[j][0], sac[i][j]);
        sac[i][j] = MFMA16(aq[i][1], bk[j][1], sac[i][j]);
      }
  }

  // ---- maskless-max softmax (|S|<~5 bounded; masked -> exp==0 exactly) ----
  {
    #pragma unroll
    for (int i = 0; i < 2; i++) {
      #pragma unroll
      for (int r = 0; r < 4; r++) {
        float vv[4];
        float sum = 0.f;
        #pragma unroll
        for (int j = 0; j < 4; j++) {
          vv[j] = __expf(sac[i][j][r] + wmv[j]);
          sum += vv[j];
        }
        sum += __shfl_xor(sum, 1);
        sum += __shfl_xor(sum, 2);
        sum += __shfl_xor(sum, 4);
        sum += __shfl_xor(sum, 8);
        const float inv = 1.0f / sum;
        const int row = w * 32 + i * 16 + quad * 4 + r;
        #pragma unroll
        for (int j = 0; j < 4; j++)
          Ps[row * 72 + j * 16 + l16] = f2bf(vv[j] * inv);
      }
    }
  }
  __syncthreads();

  // ---- O = P V ----
  f32x4 oac[2][4];
  #pragma unroll
  for (int i = 0; i < 2; i++)
    #pragma unroll
    for (int j = 0; j < 4; j++) oac[i][j] = zero4;
  {
    short8 ap[2][2], bv[4][2];
    #pragma unroll
    for (int i = 0; i < 2; i++)
      #pragma unroll
      for (int kb = 0; kb < 2; kb++)
        ap[i][kb] = *(short8*)&Ps[(w * 32 + i * 16 + l16) * 72 + kb * 32 + quad * 8];
    #pragma unroll
    for (int j = 0; j < 4; j++)
      #pragma unroll
      for (int kb = 0; kb < 2; kb++)
        bv[j][kb] = *(short8*)&Vs[(j * 16 + l16) * 72 + kb * 32 + quad * 8];
    #pragma unroll
    for (int i = 0; i < 2; i++)
      #pragma unroll
      for (int j = 0; j < 4; j++) {
        oac[i][j] = MFMA16(ap[i][0], bv[j][0], oac[i][j]);
        oac[i][j] = MFMA16(ap[i][1], bv[j][1], oac[i][j]);
      }
  }
  __syncthreads();  // K/V reads complete before O overlay write
  #pragma unroll
  for (int i = 0; i < 2; i++)
    #pragma unroll
    for (int j = 0; j < 4; j++)
      #pragma unroll
      for (int r = 0; r < 4; r++)
        Os[(w * 32 + i * 16 + quad * 4 + r) * 72 + j * 16 + l16] = f2bf(oac[i][j][r]);
  __syncthreads();

  // ---- wh store: 8 lanes/row x 16B -> 128B-contiguous segments ----
  {
    const int c8 = (tid & 7) * 8;
    #pragma unroll
    for (int i = 0; i < 4; i++) {
      const int row = i * 32 + (tid >> 3);
      short* dst = wh + (((size_t)(b * 128 + row)) * 32 + s) * 768 + h * 64;
      *(short8*)(dst + c8) = *(const short8*)&Os[row * 72 + c8];
    }
  }
}

// ---------------------------------------------------------------------------
// whc[h, bq, k] = sum_s p2[bq,h,s] * wh[bq,s,k]   (bf16 out)
// Sentence-attention probs p2 computed in-block (fused from wattn_sp):
// identical dot/softmax arithmetic, overlapped with wh staging.
// ---------------------------------------------------------------------------
__global__ __launch_bounds__(256)
void whc_kernel(const short* __restrict__ wh, const float* __restrict__ sq,
                const float* __restrict__ sk, const int* __restrict__ sent_mask,
                short* __restrict__ whc) {
  __shared__ __align__(16) short whs[32 * 776];  // pad 768->776: conflict-free reads
  __shared__ float p2s[384];                     // [hh][ss]
  const int bq = blockIdx.x, tid = threadIdx.x;
  const int b = bq >> 7;
  const short8* src = (const short8*)(wh + (size_t)bq * 24576);
  for (int t = tid; t < 3072; t += 256) {
    const int row = t / 96, c8 = (t % 96) * 8;
    *(short8*)&whs[row * 776 + c8] = src[t];
  }
  // sentence scores (same arithmetic as the former wattn_sp branch)
  for (int p = tid; p < 384; p += 256) {
    const int hh = p >> 5, ss = p & 31;
    const float4* a = (const float4*)(sq + (size_t)bq * 768 + hh * 64);
    const float4* c = (const float4*)(sk + ((size_t)(b * 32 + ss)) * 768 + hh * 64);
    float d = 0.f;
    #pragma unroll
    for (int i = 0; i < 16; i++) {
      const float4 av = a[i], cv = c[i];
      d += av.x * cv.x + av.y * cv.y + av.z * cv.z + av.w * cv.w;
    }
    d = d * 0.125f + (1.0f - (float)sent_mask[bq * 32 + ss]) * -10000.0f;
    p2s[p] = d;
  }
  __syncthreads();
  if (tid < 192) {
    // 12 heads x 16 lanes; each lane owns 2 of the 32 sentence scores.
    const int hh = tid >> 4, l = tid & 15;
    const float v0 = p2s[hh * 32 + l], v1 = p2s[hh * 32 + 16 + l];
    float mx = fmaxf(v0, v1);
    #pragma unroll
    for (int d = 1; d < 16; d <<= 1) mx = fmaxf(mx, __shfl_xor(mx, d, 16));
    const float e0 = __expf(v0 - mx), e1 = __expf(v1 - mx);
    float sum = e0 + e1;
    #pragma unroll
    for (int d = 1; d < 16; d <<= 1) sum += __shfl_xor(sum, d, 16);
    const float inv = 1.0f / sum;
    p2s[hh * 32 + l] = e0 * inv;
    p2s[hh * 32 + 16 + l] = e1 * inv;
  }
  __syncthreads();

  float acc[3][12];
  #pragma unroll
  for (int kk = 0; kk < 3; kk++)
    #pragma unroll
    for (int h = 0; h < 12; h++) acc[kk][h] = 0.f;

  for (int s = 0; s < 32; s++) {
    float p2r[12];
    #pragma unroll
    for (int h = 0; h < 12; h++) p2r[h] = p2s[h * 32 + s];
    #pragma unroll
    for (int kk = 0; kk < 3; kk++) {
      const float wv = bf2f(whs[s * 776 + kk * 256 + tid]);
      #pragma unroll
      for (int h = 0; h < 12; h++) acc[kk][h] += p2r[h] * wv;
    }
  }
  #pragma unroll
  for (int h = 0; h < 12; h++)
    #pragma unroll
    for (int kk = 0; kk < 3; kk++)
      whc[((size_t)h * 1024 + bq) * 768 + kk * 256 + tid] = f2bf(acc[kk][h]);
}

// ---------------------------------------------------------------------------
// outg: per-head GEMM  out[bq, h*64+d] = whc[h,bq,:] @ sv_w[:, h*64+d] + sv_b
// grid (16, 12): 64x64 tile, BK=32, 192 blocks. Waves 2x2; acc[2][2].
// ---------------------------------------------------------------------------
__global__ __launch_bounds__(256)
void outg(const short* __restrict__ whc, const short* __restrict__ WTsv,
          const float* __restrict__ sv_b, float* __restrict__ out) {
  const int K = 768;
  __shared__ __align__(16) short As[64 * 32];
  __shared__ __align__(16) short Bs[64 * 32];
  const int tid = threadIdx.x;
  const int m0 = blockIdx.x * 64, h = blockIdx.y;
  const int w = tid >> 6, lane = tid & 63, quad = lane >> 4, l16 = lane & 15;
  const int wm = (w >> 1) * 32, wn = (w & 1) * 32;

  // staging: wave w covers 16 rows (w*16 + lane/4), 4 lanes x 16B per row
  const int grow = w * 16 + (lane >> 2);
  const int kc = (lane & 3) * 8;
  const short* ag = whc + ((size_t)h * 1024 + m0 + grow) * K + kc;
  short* al = &As[(w * 16) * 32];
  const short* bg = WTsv + (size_t)(h * 64 + grow) * K + kc;
  short* bl = &Bs[(w * 16) * 32];

  const f32x4 zero4 = {0.f, 0.f, 0.f, 0.f};
  f32x4 acc[2][2];
  #pragma unroll
  for (int i = 0; i < 2; i++)
    #pragma unroll
    for (int j = 0; j < 2; j++) acc[i][j] = zero4;

  for (int k0 = 0; k0 < K; k0 += 32) {
    __syncthreads();
    async_load16(ag, al);
    async_load16(bg, bl);
    ag += 32;
    bg += 32;
    __syncthreads();
    short8 af[2], bf[2];
    #pragma unroll
    for (int i = 0; i < 2; i++)
      af[i] = *(short8*)&As[(wm + i * 16 + l16) * 32 + quad * 8];
    #pragma unroll
    for (int j = 0; j < 2; j++)
      bf[j] = *(short8*)&Bs[(wn + j * 16 + l16) * 32 + quad * 8];
    #pragma unroll
    for (int i = 0; i < 2; i++)
      #pragma unroll
      for (int j = 0; j < 2; j++)
        acc[i][j] = MFMA16(af[i], bf[j], acc[i][j]);
  }

  #pragma unroll
  for (int i = 0; i < 2; i++) {
    #pragma unroll
    for (int j = 0; j < 2; j++) {
      const int col = h * 64 + wn + j * 16 + l16;
      const float bv = sv_b[col];
      #pragma unroll
      for (int r = 0; r < 4; r++) {
        const int g = m0 + wm + i * 16 + quad * 4 + r;
        out[(size_t)g * 768 + col] = acc[i][j][r] + bv;
      }
    }
  }
}

// ---------------------------------------------------------------------------
extern "C" void kernel_launch(void* const* d_in, const int* in_sizes, int n_in,
                              void* d_out, int out_size, void* d_ws, size_t ws_size,
                              hipStream_t stream) {
  (void)in_sizes; (void)n_in; (void)out_size; (void)ws_size;
  const float* q_in      = (const float*)d_in[0];   // [8,128,768]
  const float* k_in      = (const float*)d_in[1];   // [8,32,64,768]
  const float* v_in      = (const float*)d_in[2];   // [8,32,64,768]
  const float* kvec      = (const float*)d_in[3];   // [8,32,768]
  const int*   word_mask = (const int*)d_in[4];     // [8,32,64]
  const int*   sent_mask = (const int*)d_in[5];     // [1024,32]
  const float* wq_w = (const float*)d_in[6],  *wq_b = (const float*)d_in[7];
  const float* wk_w = (const float*)d_in[8],  *wk_b = (const float*)d_in[9];
  const float* wv_w = (const float*)d_in[10], *wv_b = (const float*)d_in[11];
  const float* sq_w = (const float*)d_in[12], *sq_b = (const float*)d_in[13];
  const float* sk_w = (const float*)d_in[14], *sk_b = (const float*)d_in[15];
  const float* sv_w = (const float*)d_in[16], *sv_b = (const float*)d_in[17];
  float* out = (float*)d_out;

  const int WELEM = 768 * 768;

  static bool s_attr_done = false;
  if (!s_attr_done) {
    (void)hipFuncSetAttribute(reinterpret_cast<const void*>(&gemm_proj),
                              hipFuncAttributeMaxDynamicSharedMemorySize, 131072);
    s_attr_done = true;
  }

  char* ws = (char*)d_ws;
  size_t off = 0;
  auto alloc = [&](size_t bytes) -> void* {
    void* p = ws + off;
    off += (bytes + 255) & ~(size_t)255;
    return p;
  };
  short* WT  = (short*)alloc((size_t)6 * 768 * 768 * 2);   // wq,sq,wk,wv,sk,sv
  short* qbf = (short*)alloc((size_t)1024 * 768 * 2);
  short* kbf = (short*)alloc((size_t)16384 * 768 * 2);
  short* vbf = (short*)alloc((size_t)16384 * 768 * 2);
  short* kvb = (short*)alloc((size_t)256 * 768 * 2);
  short* qp  = (short*)alloc((size_t)1024 * 768 * 2);      // pre-scaled by 1/8
  short* kp  = (short*)alloc((size_t)16384 * 768 * 2);
  short* vT  = (short*)alloc((size_t)16384 * 768 * 2);     // [b,s,h,d,t]
  float* sqp = (float*)alloc((size_t)1024 * 768 * 4);
  float* skp = (float*)alloc((size_t)256 * 768 * 4);
  short* wh  = (short*)alloc((size_t)32768 * 768 * 2);     // 50.3 MB
  short* whc = (short*)alloc((size_t)12 * 1024 * 768 * 2); // 18.9 MB [h,bq,k]

  // 1: weight transposes (short4 stores) + activation converts
  prep<<<dim3(16224), 256, 0, stream>>>(wq_w, sq_w, wk_w, wv_w, sk_w, sv_w, WT,
                                        q_in, k_in, v_in, kvec, qbf, kbf, vbf, kvb);
  // 2: ALL projections (z<2: kv 256^2 8-phase bodies; z==2: q+sq,sk small)
  gemm_proj<<<dim3(64, 3, 3), 512, 131072, stream>>>(
      kbf, vbf, qbf, kvb, WT, wk_b, wv_b, wq_b, sq_b, sk_b,
      kp, vT, qp, sqp, skp);
  // 3: word attention (3072 blocks; sentence-probs fused into whc)
  wattn_sp<<<dim3(3072), 256, 0, stream>>>(qp, kp, vT, word_mask, wh);
  // 4: sentence probs + contraction over s (commutes with sv projection)
  whc_kernel<<<dim3(1024), 256, 0, stream>>>(wh, sqp, skp, sent_mask, whc);
  // 5: per-head output GEMM -> out (192 blocks, 64x64 tiles)
  outg<<<dim3(16, 12), 256, 0, stream>>>(whc, WT + 5 * WELEM, sv_b, out);
}

// Round 12
// 295.032 us; speedup vs baseline: 1.1277x; 1.0109x over previous
//
#include <hip/hip_runtime.h>
#include <hip/hip_bf16.h>

// Problem constants: BS=8, Q=128, S1=32, S2=64, H=768, NH=12, DH=64.

typedef __attribute__((ext_vector_type(8))) short short8;
typedef __attribute__((ext_vector_type(4))) short short4v;
typedef __attribute__((ext_vector_type(4))) float f32x4;

__device__ __forceinline__ short f2bf(float f) {
  __hip_bfloat16 b = __float2bfloat16(f);
  return __builtin_bit_cast(short, b);
}
__device__ __forceinline__ float bf2f(short s) {
  __hip_bfloat16 b = __builtin_bit_cast(__hip_bfloat16, s);
  return __bfloat162float(b);
}

#define MFMA16(a, b, c) __builtin_amdgcn_mfma_f32_16x16x32_bf16((a), (b), (c), 0, 0, 0)

// async 16B/lane global->LDS (wave-uniform LDS base; HW adds lane*16)
__device__ __forceinline__ void async_load16(const void* g, void* l) {
  auto l3 = (__attribute__((address_space(3))) void*)(uintptr_t)(
      reinterpret_cast<uintptr_t>(l));
  auto g1 = (const __attribute__((address_space(1))) void*)g;
  __builtin_amdgcn_global_load_lds(g1, l3, 16, 0, 0);
}

// raw barrier (no implicit vmcnt(0) drain) + compiler memory fence
#define KBAR()                                      \
  do {                                              \
    asm volatile("" ::: "memory");                  \
    __builtin_amdgcn_s_barrier();                   \
    asm volatile("" ::: "memory");                  \
  } while (0)
#define VMW(N) asm volatile("s_waitcnt vmcnt(" #N ")" ::: "memory")

// ---------------------------------------------------------------------------
// prep: blocks [0,3456) = 6 weight transposes (fp32 -> bf16, WT[n][k]),
//       transposed store vectorized to short4 (8B/lane, 1 store/thread);
//       blocks [3456,16224) = one-shot fp32->bf16 convert of q/k/v/kvec.
// ---------------------------------------------------------------------------
__global__ __launch_bounds__(256)
void prep(const float* __restrict__ w0, const float* __restrict__ w1,
          const float* __restrict__ w2, const float* __restrict__ w3,
          const float* __restrict__ w4, const float* __restrict__ w5,
          short* __restrict__ WT,
          const float* __restrict__ q_in, const float* __restrict__ k_in,
          const float* __restrict__ v_in, const float* __restrict__ kvec,
          short* __restrict__ qbf, short* __restrict__ kbf,
          short* __restrict__ vbf, short* __restrict__ kvb) {
  const int id = blockIdx.x;
  const int tid = threadIdx.x;
  if (id < 3456) {
    __shared__ float tile[32][33];
    const int zz = id / 576, r = id % 576;
    const float* W = (zz == 0) ? w0 : (zz == 1) ? w1 : (zz == 2) ? w2
                   : (zz == 3) ? w3 : (zz == 4) ? w4 : w5;
    short* WTo = WT + (size_t)zz * 768 * 768;
    const int bx = (r % 24) * 32, by = (r / 24) * 32;
    const int tx = tid & 31, ty = tid >> 5;  // 32 x 8
    #pragma unroll
    for (int i = 0; i < 32; i += 8)
      tile[ty + i][tx] = W[(size_t)(by + ty + i) * 768 + bx + tx];
    __syncthreads();
    // transposed store: WTo[bx+n][by+m] = tile[m][n]; thread -> (n=tid>>3,
    // m = (tid&7)*4 .. +3) => one aligned short4 store per thread.
    const int r2 = tid >> 3;        // output row within tile (0..31)
    const int cg = (tid & 7) * 4;   // output col group (0,4,..,28)
    __align__(8) short t4[4];
    #pragma unroll
    for (int k2 = 0; k2 < 4; k2++) t4[k2] = f2bf(tile[cg + k2][r2]);
    *(short4v*)&WTo[(size_t)(bx + r2) * 768 + by + cg] = *(short4v*)t4;
    return;
  }
  // ---- cvt: short8 units: q 98304 | k 1572864 | v 1572864 | kvec 24576 ----
  const int i = (id - 3456) * 256 + tid;
  const float* src;
  short* dst;
  int idx;
  if (i < 98304)        { src = q_in; dst = qbf; idx = i; }
  else if (i < 1671168) { src = k_in; dst = kbf; idx = i - 98304; }
  else if (i < 3244032) { src = v_in; dst = vbf; idx = i - 1671168; }
  else                  { src = kvec; dst = kvb; idx = i - 3244032; }
  const float4* s = (const float4*)src + (size_t)idx * 2;
  const float4 a = s[0], b = s[1];
  __align__(16) short tmp[8] = {f2bf(a.x), f2bf(a.y), f2bf(a.z), f2bf(a.w),
                                f2bf(b.x), f2bf(b.y), f2bf(b.z), f2bf(b.w)};
  *((short8*)dst + idx) = *(short8*)tmp;
}

// ---------------------------------------------------------------------------
// All projections, one launch, grid (64, 3, 3), 512 threads, 128 KiB dyn LDS:
//   z<2 : kv GEMM, 256x256 tile, BK=64, 8-phase schedule (R4-proven body).
//   z==2: EXACT gemm_small body (BK=32, 256 active threads). 108 blocks.
// ---------------------------------------------------------------------------
__global__ __launch_bounds__(512, 2)
void gemm_proj(const short* __restrict__ kbf, const short* __restrict__ vbf,
               const short* __restrict__ qbf, const short* __restrict__ kvb,
               const short* __restrict__ WT6,
               const float* __restrict__ wk_b, const float* __restrict__ wv_b,
               const float* __restrict__ wq_b, const float* __restrict__ sq_b,
               const float* __restrict__ sk_b,
               short* __restrict__ kp, short* __restrict__ vT,
               short* __restrict__ qp, float* __restrict__ sqp,
               float* __restrict__ skp) {
  const int K = 768, WELEM = 768 * 768;
  extern __shared__ __align__(16) char smem_c[];
  short* smem = (short*)smem_c;
  const int tid = threadIdx.x;
  const int w = tid >> 6, lane = tid & 63, quad = lane >> 4, l16 = lane & 15;
  const f32x4 zero4 = {0.f, 0.f, 0.f, 0.f};

  if (blockIdx.z < 2) {
    // ================= kv branch: 256^2 tile, 8-phase pipeline =============
    short* LA = smem;                  // [2 buf][256 rows][64 cols] bf16
    short* LB = smem + 2 * 256 * 64;   // [2 buf][256 rows][64 cols] bf16
    const int z = blockIdx.z;
    const short* Ag = z ? vbf : kbf;
    const short* Bg = z ? (WT6 + 3 * WELEM) : (WT6 + 2 * WELEM);
    const float* bias = z ? wv_b : wk_b;
    const int m0 = blockIdx.x * 256, n0 = blockIdx.y * 256;
    const int wr = w >> 2, wc = w & 3;  // 2 x 4 wave grid; wave tile 128x64

    // staging geometry: thread covers row (w*8 + lane/8), swizzled chunk
    // LDS[r][c] = G[r][c ^ (r&7)]  (chunk = 8 bf16 = 16B)
    const int srow = lane >> 3;              // 0..7
    const int schk = (lane & 7) ^ srow;      // pre-swizzled global chunk
    const short* ag0 = Ag + (size_t)(m0 + w * 8 + srow) * K + schk * 8;
    const short* bg0 = Bg + (size_t)(n0 + w * 8 + srow) * K + schk * 8;
    short* la0 = LA + (w * 8) * 64;          // wave-uniform LDS bases
    short* lb0 = LB + (w * 8) * 64;
    const int fsw = l16 & 7;                 // read-side swizzle (row&7)

    f32x4 acc[8][4];
    #pragma unroll
    for (int i = 0; i < 8; i++)
      #pragma unroll
      for (int j = 0; j < 4; j++) acc[i][j] = zero4;

    // stage one half-tile (128 rows x 64 cols) = 2 x global_load_lds / thread
    auto STG1 = [&](int op, int h, int kt) {
      if (kt >= 12) kt -= 2;  // tail: idempotent re-stage (same buf, same data)
      const int buf = kt & 1;
      const short* g = (op ? bg0 : ag0) + (size_t)h * 128 * K + (size_t)kt * 64;
      short* lb = (op ? lb0 : la0) + buf * 16384 + h * (128 * 64);
      async_load16(g, lb);
      async_load16(g + (size_t)64 * K, lb + 64 * 64);
    };

    short8 af[4][2];        // A frags of current IH: 4 i x 2 kb
    short8 bfr[2][2][2];    // B frags load-once: [JH][j][kb]

#define LDA_(BUF, IH)                                                        \
  _Pragma("unroll") for (int i = 0; i < 4; i++)                              \
    _Pragma("unroll") for (int kb = 0; kb < 2; kb++)                         \
      af[i][kb] = *(const short8*)&LA[(BUF)*16384 +                          \
          (wr * 128 + (IH)*64 + i * 16 + l16) * 64 +                         \
          (((kb * 4 + quad) ^ fsw) * 8)];
#define LDB_(BUF, JH)                                                        \
  _Pragma("unroll") for (int j = 0; j < 2; j++)                              \
    _Pragma("unroll") for (int kb = 0; kb < 2; kb++)                         \
      bfr[JH][j][kb] = *(const short8*)&LB[(BUF)*16384 +                     \
          (wc * 64 + (JH)*32 + j * 16 + l16) * 64 +                          \
          (((kb * 4 + quad) ^ fsw) * 8)];
#define MM_(IH, JH)                                                          \
  __builtin_amdgcn_s_setprio(1);                                             \
  _Pragma("unroll") for (int i = 0; i < 4; i++)                              \
    _Pragma("unroll") for (int j = 0; j < 2; j++) {                          \
      acc[(IH)*4 + i][(JH)*2 + j] =                                          \
          MFMA16(af[i][0], bfr[JH][j][0], acc[(IH)*4 + i][(JH)*2 + j]);      \
      acc[(IH)*4 + i][(JH)*2 + j] =                                          \
          MFMA16(af[i][1], bfr[JH][j][1], acc[(IH)*4 + i][(JH)*2 + j]);      \
    }                                                                        \
  __builtin_amdgcn_s_setprio(0);

    // ---- prologue: tile0 (8 loads) + B(1) (4 loads); drain tile0 ----
    STG1(0, 0, 0); STG1(0, 1, 0); STG1(1, 0, 0); STG1(1, 1, 0);
    STG1(1, 0, 1); STG1(1, 1, 1);
    VMW(4);   // tile 0 landed; B(1) in flight
    KBAR();

    // ---- main loop: 12 K-tiles = 6 iterations x 8 phases (R4 schedule) ----
    #pragma unroll 1
    for (int it = 0; it < 6; ++it) {
      const int o = 2 * it + 1, e2 = 2 * it + 2, o2 = 2 * it + 3;
      // P1
      LDA_(0, 0); LDB_(0, 0); STG1(0, 0, o); KBAR(); MM_(0, 0); KBAR();
      // P2
      LDB_(0, 1); STG1(0, 1, o); KBAR(); MM_(0, 1); KBAR();
      // P3
      LDA_(0, 1); STG1(1, 0, e2); KBAR(); MM_(1, 1); KBAR();
      // P4
      STG1(1, 1, e2); KBAR(); MM_(1, 0); VMW(4); KBAR();
      // P5
      LDA_(1, 0); LDB_(1, 0); STG1(0, 0, e2); KBAR(); MM_(0, 0); KBAR();
      // P6
      LDB_(1, 1); STG1(0, 1, e2); KBAR(); MM_(0, 1); KBAR();
      // P7
      LDA_(1, 1); STG1(1, 0, o2); KBAR(); MM_(1, 1); KBAR();
      // P8
      STG1(1, 1, o2); KBAR(); MM_(1, 0); VMW(4); KBAR();
    }
#undef LDA_
#undef LDB_
#undef MM_
    VMW(0);  // drain trailing idempotent stages before epilogue/endpgm

    // ---- epilogue ----
    if (z == 0) {
      #pragma unroll
      for (int I = 0; I < 8; I++)
        #pragma unroll
        for (int J = 0; J < 4; J++) {
          const int col = n0 + wc * 64 + J * 16 + l16;
          const float bv = bias[col];
          #pragma unroll
          for (int r = 0; r < 4; r++) {
            const int g = m0 + wr * 128 + I * 16 + quad * 4 + r;
            kp[(size_t)g * 768 + col] = f2bf(acc[I][J][r] + bv);
          }
        }
    } else {
      const int hh = (n0 >> 6) + wc;           // wave-constant head
      #pragma unroll
      for (int I = 0; I < 8; I++) {
        const int bs_ = (m0 >> 6) + wr * 2 + (I >> 2);  // global sentence
        const int t0 = (I & 3) * 16 + quad * 4;         // token base
        #pragma unroll
        for (int J = 0; J < 4; J++) {
          const int dd = J * 16 + l16;
          const float bv = bias[hh * 64 + dd];
          __align__(8) short tmp[4];
          #pragma unroll
          for (int r = 0; r < 4; r++) tmp[r] = f2bf(acc[I][J][r] + bv);
          *(short4v*)&vT[(((size_t)bs_ * 12 + hh) * 64 + dd) * 64 + t0] =
              *(short4v*)tmp;
        }
      }
    }
    return;
  }

  // ================= small branch (gemm_small body, BK=32) =================
  {
    const int id = blockIdx.x + 64 * blockIdx.y;  // 0..191
    if (id >= 108) return;
    short* As = smem;               // [128*32]
    short* Bs = smem + 128 * 32;    // [128*32]
    const int qmode = (id < 96);
    const int r = qmode ? id : (id - 96);
    const int bx = qmode ? (r % 8) : (r % 2);
    const int by = qmode ? (r / 8) : (r / 2);
    const short* A = qmode ? qbf : kvb;
    const short* WT = qmode ? (WT6 + 0 * WELEM) : (WT6 + 4 * WELEM);

    const int wm = (w >> 1) * 64, wn = (w & 1) * 64;  // valid for tid<256
    const int m0 = bx * 128, n0 = by * 128;
    const int grow = w * 32 + (lane >> 2);
    const int kc = (lane & 3) * 8;
    const short* ag = A + (size_t)(m0 + grow) * K + kc;
    const short* bg = WT + (size_t)(n0 + grow) * K + kc;
    short* al = &As[(w * 32) * 32];
    short* bl = &Bs[(w * 32) * 32];

    f32x4 acc[4][4];
    #pragma unroll
    for (int i = 0; i < 4; i++)
      #pragma unroll
      for (int j = 0; j < 4; j++) acc[i][j] = zero4;

    for (int k0 = 0; k0 < K; k0 += 32) {
      __syncthreads();
      if (tid < 256) {
        async_load16(ag, al);
        async_load16(ag + (size_t)16 * K, al + 16 * 32);
        async_load16(bg, bl);
        async_load16(bg + (size_t)16 * K, bl + 16 * 32);
      }
      ag += 32;
      bg += 32;
      __syncthreads();
      if (tid < 256) {
        short8 af[4], bf[4];
        #pragma unroll
        for (int i = 0; i < 4; i++)
          af[i] = *(short8*)&As[(wm + i * 16 + l16) * 32 + quad * 8];
        #pragma unroll
        for (int j = 0; j < 4; j++)
          bf[j] = *(short8*)&Bs[(wn + j * 16 + l16) * 32 + quad * 8];
        #pragma unroll
        for (int i = 0; i < 4; i++)
          #pragma unroll
          for (int j = 0; j < 4; j++)
            acc[i][j] = MFMA16(af[i], bf[j], acc[i][j]);
      }
    }
    if (tid >= 256) return;

    #pragma unroll
    for (int i = 0; i < 4; i++) {
      #pragma unroll
      for (int j = 0; j < 4; j++) {
        const int col = n0 + wn + j * 16 + l16;
        const float bv = qmode ? ((col < 768) ? wq_b[col] : sq_b[col - 768])
                               : sk_b[col];
        #pragma unroll
        for (int r4 = 0; r4 < 4; r4++) {
          const int g = m0 + wm + i * 16 + quad * 4 + r4;
          const float v = acc[i][j][r4] + bv;
          if (qmode) {
            if (col < 768) qp[(size_t)g * 768 + col] = f2bf(v * 0.125f);
            else sqp[(size_t)g * 768 + (col - 768)] = v;
          } else {
            skp[(size_t)g * 768 + col] = v;
          }
        }
      }
    }
  }
}

// ---------------------------------------------------------------------------
// 3072 blocks: word-level attention per (b, s, h):
//   S = Qs Kt (Q pre-scaled by 1/8); maskless-max softmax; O = P V -> wh
//   Q-fragment + word-mask global loads hoisted above the staging barrier.
// ---------------------------------------------------------------------------
__global__ __launch_bounds__(256)
void wattn_sp(const short* __restrict__ q_proj, const short* __restrict__ k_proj,
              const short* __restrict__ vT, const int* __restrict__ word_mask,
              short* __restrict__ wh) {
  __shared__ __align__(16) short KVs[128 * 72];  // K rows 0-63, Vt rows 64-127; O overlay
  __shared__ __align__(16) short Ps[128 * 72];   // P bf16
  const int bid = blockIdx.x;
  const int tid = threadIdx.x;

  short* Ks = KVs;
  short* Vs = KVs + 64 * 72;
  short* Os = KVs;
  const int h = bid % 12, s = (bid / 12) % 32, b = bid / (12 * 32);
  const int w = tid >> 6, lane = tid & 63, quad = lane >> 4, l16 = lane & 15;
  const f32x4 zero4 = {0.f, 0.f, 0.f, 0.f};

  // ---- hoisted global loads (independent of LDS staging): Q frags + mask ----
  short8 aq[2][2];
  float wmv[4];
  {
    #pragma unroll
    for (int i = 0; i < 2; i++)
      #pragma unroll
      for (int kb = 0; kb < 2; kb++)
        aq[i][kb] = *(const short8*)(q_proj +
            ((size_t)(b * 128 + w * 32 + i * 16 + l16)) * 768 + h * 64 + kb * 32 + quad * 8);
    const int* wmp = word_mask + (b * 32 + s) * 64;
    #pragma unroll
    for (int j = 0; j < 4; j++)
      wmv[j] = (1.0f - (float)wmp[j * 16 + l16]) * -10000.0f;
  }

  // ---- stage K (tid<128) and Vt (tid>=128): 8 lanes/row x 16B ----
  {
    const int t2 = tid & 127;
    const int row8 = t2 >> 3;      // 0..15
    const int c8 = (t2 & 7) * 8;   // short offset within 64
    if (tid < 128) {
      const short* src = k_proj + ((size_t)((b * 32 + s) * 64)) * 768 + h * 64 + c8;
      #pragma unroll
      for (int i = 0; i < 4; i++) {
        const int r = row8 + i * 16;
        *(short8*)&Ks[r * 72 + c8] = *(const short8*)(src + (size_t)r * 768);
      }
    } else {
      const short* src = vT + ((size_t)((b * 32 + s) * 12 + h)) * 4096 + c8;
      #pragma unroll
      for (int i = 0; i < 4; i++) {
        const int r = row8 + i * 16;
        *(short8*)&Vs[r * 72 + c8] = *(const short8*)(src + (size_t)r * 64);
      }
    }
  }
  __syncthreads();

  // ---- S = Qs Kt ----
  f32x4 sac[2][4];
  #pragma unroll
  for (int i = 0; i < 2; i++)
    #pragma unroll
    for (int j = 0; j < 4; j++) sac[i][j] = zero4;
  {
    short8 bk[4][2];
    #pragma unroll
    for (int j = 0; j < 4; j++)
      #pragma unroll
      for (int kb = 0; kb < 2; kb++)
        bk[j][kb] = *(short8*)&Ks[(j * 16 + l16) * 72 + kb * 32 + quad * 8];
    #pragma unroll
    for (int i = 0; i < 2; i++)
      #pragma unroll
      for (int j = 0; j < 4; j++) {
        sac[i][j] = MFMA16(aq[i][0], bk[j][0], sac[i][j]);
        sac[i][j] = MFMA16(aq[i][1], bk[j][1], sac[i][j]);
      }
  }

  // ---- maskless-max softmax (|S|<~5 bounded; masked -> exp==0 exactly) ----
  {
    #pragma unroll
    for (int i = 0; i < 2; i++) {
      #pragma unroll
      for (int r = 0; r < 4; r++) {
        float vv[4];
        float sum = 0.f;
        #pragma unroll
        for (int j = 0; j < 4; j++) {
          vv[j] = __expf(sac[i][j][r] + wmv[j]);
          sum += vv[j];
        }
        sum += __shfl_xor(sum, 1);
        sum += __shfl_xor(sum, 2);
        sum += __shfl_xor(sum, 4);
        sum += __shfl_xor(sum, 8);
        const float inv = 1.0f / sum;
        const int row = w * 32 + i * 16 + quad * 4 + r;
        #pragma unroll
        for (int j = 0; j < 4; j++)
          Ps[row * 72 + j * 16 + l16] = f2bf(vv[j] * inv);
      }
    }
  }
  __syncthreads();

  // ---- O = P V ----
  f32x4 oac[2][4];
  #pragma unroll
  for (int i = 0; i < 2; i++)
    #pragma unroll
    for (int j = 0; j < 4; j++) oac[i][j] = zero4;
  {
    short8 ap[2][2], bv[4][2];
    #pragma unroll
    for (int i = 0; i < 2; i++)
      #pragma unroll
      for (int kb = 0; kb < 2; kb++)
        ap[i][kb] = *(short8*)&Ps[(w * 32 + i * 16 + l16) * 72 + kb * 32 + quad * 8];
    #pragma unroll
    for (int j = 0; j < 4; j++)
      #pragma unroll
      for (int kb = 0; kb < 2; kb++)
        bv[j][kb] = *(short8*)&Vs[(j * 16 + l16) * 72 + kb * 32 + quad * 8];
    #pragma unroll
    for (int i = 0; i < 2; i++)
      #pragma unroll
      for (int j = 0; j < 4; j++) {
        oac[i][j] = MFMA16(ap[i][0], bv[j][0], oac[i][j]);
        oac[i][j] = MFMA16(ap[i][1], bv[j][1], oac[i][j]);
      }
  }
  __syncthreads();  // K/V reads complete before O overlay write
  #pragma unroll
  for (int i = 0; i < 2; i++)
    #pragma unroll
    for (int j = 0; j < 4; j++)
      #pragma unroll
      for (int r = 0; r < 4; r++)
        Os[(w * 32 + i * 16 + quad * 4 + r) * 72 + j * 16 + l16] = f2bf(oac[i][j][r]);
  __syncthreads();

  // ---- wh store: 8 lanes/row x 16B -> 128B-contiguous segments ----
  {
    const int c8 = (tid & 7) * 8;
    #pragma unroll
    for (int i = 0; i < 4; i++) {
      const int row = i * 32 + (tid >> 3);
      short* dst = wh + (((size_t)(b * 128 + row)) * 32 + s) * 768 + h * 64;
      *(short8*)(dst + c8) = *(const short8*)&Os[row * 72 + c8];
    }
  }
}

// ---------------------------------------------------------------------------
// whc[h, bq, k] = sum_s p2[bq,h,s] * wh[bq,s,k]   (bf16 out)
// Sentence-attention probs p2 computed in-block (fused): identical dot/softmax
// arithmetic, overlapped with wh staging.
// ---------------------------------------------------------------------------
__global__ __launch_bounds__(256)
void whc_kernel(const short* __restrict__ wh, const float* __restrict__ sq,
                const float* __restrict__ sk, const int* __restrict__ sent_mask,
                short* __restrict__ whc) {
  __shared__ __align__(16) short whs[32 * 776];  // pad 768->776: conflict-free reads
  __shared__ float p2s[384];                     // [hh][ss]
  const int bq = blockIdx.x, tid = threadIdx.x;
  const int b = bq >> 7;
  const short8* src = (const short8*)(wh + (size_t)bq * 24576);
  for (int t = tid; t < 3072; t += 256) {
    const int row = t / 96, c8 = (t % 96) * 8;
    *(short8*)&whs[row * 776 + c8] = src[t];
  }
  // sentence scores (same arithmetic as the former wattn_sp branch)
  for (int p = tid; p < 384; p += 256) {
    const int hh = p >> 5, ss = p & 31;
    const float4* a = (const float4*)(sq + (size_t)bq * 768 + hh * 64);
    const float4* c = (const float4*)(sk + ((size_t)(b * 32 + ss)) * 768 + hh * 64);
    float d = 0.f;
    #pragma unroll
    for (int i = 0; i < 16; i++) {
      const float4 av = a[i], cv = c[i];
      d += av.x * cv.x + av.y * cv.y + av.z * cv.z + av.w * cv.w;
    }
    d = d * 0.125f + (1.0f - (float)sent_mask[bq * 32 + ss]) * -10000.0f;
    p2s[p] = d;
  }
  __syncthreads();
  if (tid < 192) {
    // 12 heads x 16 lanes; each lane owns 2 of the 32 sentence scores.
    const int hh = tid >> 4, l = tid & 15;
    const float v0 = p2s[hh * 32 + l], v1 = p2s[hh * 32 + 16 + l];
    float mx = fmaxf(v0, v1);
    #pragma unroll
    for (int d = 1; d < 16; d <<= 1) mx = fmaxf(mx, __shfl_xor(mx, d, 16));
    const float e0 = __expf(v0 - mx), e1 = __expf(v1 - mx);
    float sum = e0 + e1;
    #pragma unroll
    for (int d = 1; d < 16; d <<= 1) sum += __shfl_xor(sum, d, 16);
    const float inv = 1.0f / sum;
    p2s[hh * 32 + l] = e0 * inv;
    p2s[hh * 32 + 16 + l] = e1 * inv;
  }
  __syncthreads();

  float acc[3][12];
  #pragma unroll
  for (int kk = 0; kk < 3; kk++)
    #pragma unroll
    for (int h = 0; h < 12; h++) acc[kk][h] = 0.f;

  for (int s = 0; s < 32; s++) {
    float p2r[12];
    #pragma unroll
    for (int h = 0; h < 12; h++) p2r[h] = p2s[h * 32 + s];
    #pragma unroll
    for (int kk = 0; kk < 3; kk++) {
      const float wv = bf2f(whs[s * 776 + kk * 256 + tid]);
      #pragma unroll
      for (int h = 0; h < 12; h++) acc[kk][h] += p2r[h] * wv;
    }
  }
  #pragma unroll
  for (int h = 0; h < 12; h++)
    #pragma unroll
    for (int kk = 0; kk < 3; kk++)
      whc[((size_t)h * 1024 + bq) * 768 + kk * 256 + tid] = f2bf(acc[kk][h]);
}

// ---------------------------------------------------------------------------
// outg: per-head GEMM  out[bq, h*64+d] = whc[h,bq,:] @ sv_w[:, h*64+d] + sv_b
// grid (16, 12): 64x64 tile, BK=64 (12 sync-iterations, was 24), kv-style
// chunk-XOR swizzled staging (verbatim kv geometry at 64-col width).
// Waves 2x2: wm=(w>>1)*32, wn=(w&1)*32; acc[2][2]. Same MFMA K-order as
// BK=32 version => bitwise-identical output.
// ---------------------------------------------------------------------------
__global__ __launch_bounds__(256)
void outg(const short* __restrict__ whc, const short* __restrict__ WTsv,
          const float* __restrict__ sv_b, float* __restrict__ out) {
  const int K = 768;
  __shared__ __align__(16) short As[64 * 64];
  __shared__ __align__(16) short Bs[64 * 64];
  const int tid = threadIdx.x;
  const int m0 = blockIdx.x * 64, h = blockIdx.y;
  const int w = tid >> 6, lane = tid & 63, quad = lane >> 4, l16 = lane & 15;
  const int wm = (w >> 1) * 32, wn = (w & 1) * 32;

  // staging: LDS[r][c] = G[r][c ^ (r&7)] (chunk = 8 bf16 = 16B);
  // thread covers rows (w*8 + lane/8) and +32, swizzled chunk (lane&7)^srow.
  const int srow = lane >> 3;
  const int schk = (lane & 7) ^ srow;
  const short* ag = whc + ((size_t)h * 1024 + m0 + w * 8 + srow) * K + schk * 8;
  const short* bg = WTsv + (size_t)(h * 64 + w * 8 + srow) * K + schk * 8;
  short* al = &As[(w * 8) * 64];
  short* bl = &Bs[(w * 8) * 64];
  const int fsw = l16 & 7;

  const f32x4 zero4 = {0.f, 0.f, 0.f, 0.f};
  f32x4 acc[2][2];
  #pragma unroll
  for (int i = 0; i < 2; i++)
    #pragma unroll
    for (int j = 0; j < 2; j++) acc[i][j] = zero4;

  for (int k0 = 0; k0 < K; k0 += 64) {
    __syncthreads();
    async_load16(ag, al);
    async_load16(ag + (size_t)32 * K, al + 32 * 64);
    async_load16(bg, bl);
    async_load16(bg + (size_t)32 * K, bl + 32 * 64);
    ag += 64;
    bg += 64;
    __syncthreads();
    short8 af[2][2], bf[2][2];
    #pragma unroll
    for (int i = 0; i < 2; i++)
      #pragma unroll
      for (int kb = 0; kb < 2; kb++)
        af[i][kb] = *(short8*)&As[(wm + i * 16 + l16) * 64 +
                                  (((kb * 4 + quad) ^ fsw) * 8)];
    #pragma unroll
    for (int j = 0; j < 2; j++)
      #pragma unroll
      for (int kb = 0; kb < 2; kb++)
        bf[j][kb] = *(short8*)&Bs[(wn + j * 16 + l16) * 64 +
                                  (((kb * 4 + quad) ^ fsw) * 8)];
    #pragma unroll
    for (int i = 0; i < 2; i++)
      #pragma unroll
      for (int j = 0; j < 2; j++) {
        acc[i][j] = MFMA16(af[i][0], bf[j][0], acc[i][j]);
        acc[i][j] = MFMA16(af[i][1], bf[j][1], acc[i][j]);
      }
  }

  #pragma unroll
  for (int i = 0; i < 2; i++) {
    #pragma unroll
    for (int j = 0; j < 2; j++) {
      const int col = h * 64 + wn + j * 16 + l16;
      const float bv = sv_b[col];
      #pragma unroll
      for (int r = 0; r < 4; r++) {
        const int g = m0 + wm + i * 16 + quad * 4 + r;
        out[(size_t)g * 768 + col] = acc[i][j][r] + bv;
      }
    }
  }
}

// ---------------------------------------------------------------------------
extern "C" void kernel_launch(void* const* d_in, const int* in_sizes, int n_in,
                              void* d_out, int out_size, void* d_ws, size_t ws_size,
                              hipStream_t stream) {
  (void)in_sizes; (void)n_in; (void)out_size; (void)ws_size;
  const float* q_in      = (const float*)d_in[0];   // [8,128,768]
  const float* k_in      = (const float*)d_in[1];   // [8,32,64,768]
  const float* v_in      = (const float*)d_in[2];   // [8,32,64,768]
  const float* kvec      = (const float*)d_in[3];   // [8,32,768]
  const int*   word_mask = (const int*)d_in[4];     // [8,32,64]
  const int*   sent_mask = (const int*)d_in[5];     // [1024,32]
  const float* wq_w = (const float*)d_in[6],  *wq_b = (const float*)d_in[7];
  const float* wk_w = (const float*)d_in[8],  *wk_b = (const float*)d_in[9];
  const float* wv_w = (const float*)d_in[10], *wv_b = (const float*)d_in[11];
  const float* sq_w = (const float*)d_in[12], *sq_b = (const float*)d_in[13];
  const float* sk_w = (const float*)d_in[14], *sk_b = (const float*)d_in[15];
  const float* sv_w = (const float*)d_in[16], *sv_b = (const float*)d_in[17];
  float* out = (float*)d_out;

  const int WELEM = 768 * 768;

  static bool s_attr_done = false;
  if (!s_attr_done) {
    (void)hipFuncSetAttribute(reinterpret_cast<const void*>(&gemm_proj),
                              hipFuncAttributeMaxDynamicSharedMemorySize, 131072);
    s_attr_done = true;
  }

  char* ws = (char*)d_ws;
  size_t off = 0;
  auto alloc = [&](size_t bytes) -> void* {
    void* p = ws + off;
    off += (bytes + 255) & ~(size_t)255;
    return p;
  };
  short* WT  = (short*)alloc((size_t)6 * 768 * 768 * 2);   // wq,sq,wk,wv,sk,sv
  short* qbf = (short*)alloc((size_t)1024 * 768 * 2);
  short* kbf = (short*)alloc((size_t)16384 * 768 * 2);
  short* vbf = (short*)alloc((size_t)16384 * 768 * 2);
  short* kvb = (short*)alloc((size_t)256 * 768 * 2);
  short* qp  = (short*)alloc((size_t)1024 * 768 * 2);      // pre-scaled by 1/8
  short* kp  = (short*)alloc((size_t)16384 * 768 * 2);
  short* vT  = (short*)alloc((size_t)16384 * 768 * 2);     // [b,s,h,d,t]
  float* sqp = (float*)alloc((size_t)1024 * 768 * 4);
  float* skp = (float*)alloc((size_t)256 * 768 * 4);
  short* wh  = (short*)alloc((size_t)32768 * 768 * 2);     // 50.3 MB (dedicated:
  short* whc = (short*)alloc((size_t)12 * 1024 * 768 * 2); // no aliasing — replay-safe)

  // 1: weight transposes (short4 stores) + activation converts
  prep<<<dim3(16224), 256, 0, stream>>>(wq_w, sq_w, wk_w, wv_w, sk_w, sv_w, WT,
                                        q_in, k_in, v_in, kvec, qbf, kbf, vbf, kvb);
  // 2: ALL projections (z<2: kv 256^2 8-phase bodies; z==2: q+sq,sk small)
  gemm_proj<<<dim3(64, 3, 3), 512, 131072, stream>>>(
      kbf, vbf, qbf, kvb, WT, wk_b, wv_b, wq_b, sq_b, sk_b,
      kp, vT, qp, sqp, skp);
  // 3: word attention (3072 blocks; sentence-probs fused into whc)
  wattn_sp<<<dim3(3072), 256, 0, stream>>>(qp, kp, vT, word_mask, wh);
  // 4: sentence probs + contraction over s (commutes with sv projection)
  whc_kernel<<<dim3(1024), 256, 0, stream>>>(wh, sqp, skp, sent_mask, whc);
  // 5: per-head output GEMM -> out (192 blocks, 64x64 tiles, BK=64)
  outg<<<dim3(16, 12), 256, 0, stream>>>(whc, WT + 5 * WELEM, sv_b, out);
}